// Round 6
// baseline (922.266 us; speedup 1.0000x reference)
//
#include <hip/hip_runtime.h>
#include <stdint.h>

#define F_IN 512
#define HF 256
#define OUT_F 2
#define BN_EPS 1e-5f
#define SCAN_B 256
#define LDSTR 36    // LDS row stride (shorts): 0 bank conflicts (measured R7)
#define NBSETUP 768 // fused front-end grid: 3 blocks/CU guaranteed co-resident

typedef __attribute__((ext_vector_type(8))) short bf16x8;
typedef __attribute__((ext_vector_type(8))) unsigned short u16x8;
typedef __attribute__((ext_vector_type(4))) float f32x4;

__device__ inline float bf2f(unsigned short u) {
    union { float f; uint32_t i; } v; v.i = ((uint32_t)u) << 16; return v.f;
}
__device__ inline unsigned short f2bf(float f) {
    union { float f; uint32_t i; } v; v.f = f;
    uint32_t r = v.i + 0x7FFFu + ((v.i >> 16) & 1u);   // RNE (finite values only)
    return (unsigned short)(r >> 16);
}

// ---------- device-scope grid barrier (sense-reversal; all blocks co-resident) ----------
__device__ inline void grid_sync(int* cnt, int* gen, int nb) {
    __syncthreads();
    if (threadIdx.x == 0) {
        __threadfence();   // release prior writes, device scope
        int g = __hip_atomic_load(gen, __ATOMIC_RELAXED, __HIP_MEMORY_SCOPE_AGENT);
        if (__hip_atomic_fetch_add(cnt, 1, __ATOMIC_ACQ_REL, __HIP_MEMORY_SCOPE_AGENT) == nb - 1) {
            __hip_atomic_store(cnt, 0, __ATOMIC_RELAXED, __HIP_MEMORY_SCOPE_AGENT);
            __hip_atomic_store(gen, g + 1, __ATOMIC_RELEASE, __HIP_MEMORY_SCOPE_AGENT);
        } else {
            while (__hip_atomic_load(gen, __ATOMIC_ACQUIRE, __HIP_MEMORY_SCOPE_AGENT) == g)
                __builtin_amdgcn_s_sleep(2);
        }
        __threadfence();   // acquire side: pull other XCDs' writes into view
    }
    __syncthreads();
}

// ---------- fused front-end: prep + x->bf16 + count + scan1 + scan3 + fill ----------
// One dispatch replaces five. Phases separated by grid_sync (device-scope fences
// handle cross-XCD visibility of the plain stores between phases).
__global__ __launch_bounds__(256, 4)
void setup_kernel(unsigned long long* __restrict__ packed,
                  const float* __restrict__ W1, unsigned short* __restrict__ W1t,
                  const float* __restrict__ W2, unsigned short* __restrict__ W2t,
                  unsigned short* __restrict__ xbf,   // [MP, F_IN]
                  unsigned short* __restrict__ bufa,  // [MP, HF] (pad rows zeroed)
                  const float* __restrict__ x,
                  const int* __restrict__ row, const int* __restrict__ col,
                  const float* __restrict__ ew,
                  int* __restrict__ csr_ptr, int* __restrict__ cursor,
                  int* __restrict__ blocksum, float* __restrict__ dinv,
                  int2* __restrict__ csr_edge,
                  int* __restrict__ bar,              // [2] zeroed by memset
                  int n, int e, int padx, int pada, int nscan, int nchunk) {
    __shared__ int tmp[SCAN_B];
    const int gsz  = gridDim.x * blockDim.x;
    const int gtid = blockIdx.x * blockDim.x + threadIdx.x;
    int* cnt = bar;
    int* gen = bar + 1;

    // ---- P0: packed init, weight transposes, pad zeroing, x -> bf16 ----
    for (int i = gtid; i < n; i += gsz) packed[i] = 1ULL << 20;  // self-loop w=1, 24.20 fx
    for (int j = gtid; j < F_IN * HF; j += gsz) {                // W1t[nn*512+k]
        int nn = j >> 9, k = j & (F_IN - 1);
        W1t[j] = f2bf(W1[(size_t)k * HF + nn]);
    }
    for (int j = gtid; j < HF * HF; j += gsz) {                  // W2t[nn*256+k]
        int nn = j >> 8, k = j & (HF - 1);
        W2t[j] = f2bf(W2[(size_t)k * HF + nn]);
    }
    for (int j = gtid; j < padx; j += gsz) xbf[(size_t)n * F_IN + j] = 0;
    for (int j = gtid; j < pada; j += gsz) bufa[(size_t)n * HF + j] = 0;
    const float4* x4 = (const float4*)x;
    for (int c = gtid; c < nchunk; c += gsz) {                   // fp32 -> bf16, 8/chunk
        float4 f0 = x4[2 * c];
        float4 f1 = x4[2 * c + 1];
        bf16x8 v;
        v[0] = (short)f2bf(f0.x); v[1] = (short)f2bf(f0.y);
        v[2] = (short)f2bf(f0.z); v[3] = (short)f2bf(f0.w);
        v[4] = (short)f2bf(f1.x); v[5] = (short)f2bf(f1.y);
        v[6] = (short)f2bf(f1.z); v[7] = (short)f2bf(f1.w);
        *(bf16x8*)(xbf + (size_t)c * 8) = v;
    }
    grid_sync(cnt, gen, (int)gridDim.x);

    // ---- P1: degree count (packed 64-bit atomics) ----
    for (int i = gtid; i < e; i += gsz) {
        unsigned long long add = (1ULL << 40)
            | (unsigned long long)__float2uint_rn(ew[i] * 1048576.0f);
        atomicAdd(&packed[col[i]], add);
    }
    grid_sync(cnt, gen, (int)gridDim.x);

    // ---- P2: block-local exclusive scan (blocks 0..nscan-1) ----
    if ((int)blockIdx.x < nscan) {
        int i = blockIdx.x * SCAN_B + threadIdx.x;
        int v = (i < n) ? (int)(packed[i] >> 40) : 0;
        tmp[threadIdx.x] = v;
        __syncthreads();
        for (int off = 1; off < SCAN_B; off <<= 1) {
            int t = 0;
            if ((int)threadIdx.x >= off) t = tmp[threadIdx.x - off];
            __syncthreads();
            if ((int)threadIdx.x >= off) tmp[threadIdx.x] += t;
            __syncthreads();
        }
        if (i < n) csr_ptr[i] = tmp[threadIdx.x] - v;      // exclusive
        if (threadIdx.x == SCAN_B - 1) blocksum[blockIdx.x] = tmp[SCAN_B - 1];
    }
    grid_sync(cnt, gen, (int)gridDim.x);

    // ---- P3: add block prefix + dinv (blocks 0..nscan-1) ----
    if ((int)blockIdx.x < nscan) {
        int t = threadIdx.x;
        tmp[t] = (t < nscan && t < (int)blockIdx.x) ? blocksum[t] : 0;
        __syncthreads();
        for (int off = SCAN_B / 2; off > 0; off >>= 1) {
            if (t < off) tmp[t] += tmp[t + off];
            __syncthreads();
        }
        int prefix = tmp[0];
        int i = blockIdx.x * SCAN_B + t;
        if (i < n) {
            int val = csr_ptr[i] + prefix;
            csr_ptr[i] = val;
            cursor[i] = val;
            float deg = (float)(packed[i] & 0xFFFFFFFFFFULL) * (1.0f / 1048576.0f);
            dinv[i] = rsqrtf(deg);   // deg >= 1 always (self-loop)
        }
        if (i == 0) csr_ptr[n] = e;
    }
    grid_sync(cnt, gen, (int)gridDim.x);

    // ---- P4: CSR fill (bucket by col, fold norm) ----
    for (int i = gtid; i < e; i += gsz) {
        int r = row[i], c = col[i];
        int pos = atomicAdd(&cursor[c], 1);
        float nrm = dinv[r] * ew[i] * dinv[c];
        csr_edge[pos] = make_int2(r, __float_as_int(nrm));
    }
}

// ---------- pipelined bf16 GEMM: C[MP,256] = A[MP,K] @ Bt[256,K]^T (R2-proven) ----------
__global__ __launch_bounds__(256)
void gemm_kernel(const unsigned short* __restrict__ A,
                 const unsigned short* __restrict__ Bt,
                 unsigned short* __restrict__ C, int K) {
    __shared__ unsigned short As[2][128 * LDSTR];
    __shared__ unsigned short Bs[2][128 * LDSTR];
    const int tid  = threadIdx.x;
    const int lane = tid & 63;
    const int wv   = tid >> 6;
    const int wrow = wv >> 1, wcol = wv & 1;
    const int m0 = blockIdx.x * 128;
    const int n0 = blockIdx.y * 128;

    const int sr = tid >> 2;          // staging row 0..63
    const int sc = (tid & 3) * 8;     // staging k-offset 0,8,16,24

    const unsigned short* pa0 = A + (size_t)(m0 + sr) * K + sc;
    const unsigned short* pa1 = A + (size_t)(m0 + sr + 64) * K + sc;
    const unsigned short* pb0 = Bt + (size_t)(n0 + sr) * K + sc;
    const unsigned short* pb1 = Bt + (size_t)(n0 + sr + 64) * K + sc;

    f32x4 zero4 = {0.0f, 0.0f, 0.0f, 0.0f};
    f32x4 acc[4][4];
    #pragma unroll
    for (int i = 0; i < 4; ++i)
        #pragma unroll
        for (int j = 0; j < 4; ++j) acc[i][j] = zero4;

    const int q8 = (lane >> 4) * 8;
    const int ml = lane & 15;

    bf16x8 va0 = *(const bf16x8*)pa0;
    bf16x8 va1 = *(const bf16x8*)pa1;
    bf16x8 vb0 = *(const bf16x8*)pb0;
    bf16x8 vb1 = *(const bf16x8*)pb1;

    const int nsteps = K >> 5;
    for (int s = 0; s < nsteps; ++s) {
        const int buf = s & 1;
        *(bf16x8*)&As[buf][sr * LDSTR + sc]        = va0;
        *(bf16x8*)&As[buf][(sr + 64) * LDSTR + sc] = va1;
        *(bf16x8*)&Bs[buf][sr * LDSTR + sc]        = vb0;
        *(bf16x8*)&Bs[buf][(sr + 64) * LDSTR + sc] = vb1;
        __syncthreads();
        if (s + 1 < nsteps) {             // prefetch next tile
            int off = (s + 1) * 32;
            va0 = *(const bf16x8*)(pa0 + off);
            va1 = *(const bf16x8*)(pa1 + off);
            vb0 = *(const bf16x8*)(pb0 + off);
            vb1 = *(const bf16x8*)(pb1 + off);
        }
        bf16x8 af[4], bfr[4];
        #pragma unroll
        for (int i = 0; i < 4; ++i)
            af[i] = *(const bf16x8*)&As[buf][(wrow * 64 + i * 16 + ml) * LDSTR + q8];
        #pragma unroll
        for (int j = 0; j < 4; ++j)
            bfr[j] = *(const bf16x8*)&Bs[buf][(wcol * 64 + j * 16 + ml) * LDSTR + q8];
        #pragma unroll
        for (int i = 0; i < 4; ++i)
            #pragma unroll
            for (int j = 0; j < 4; ++j)
                acc[i][j] = __builtin_amdgcn_mfma_f32_16x16x32_bf16(af[i], bfr[j], acc[i][j], 0, 0, 0);
    }

    // C store (bf16): col=lane&15, row=(lane>>4)*4+reg
    const int q4 = (lane >> 4) * 4;
    #pragma unroll
    for (int i = 0; i < 4; ++i) {
        #pragma unroll
        for (int j = 0; j < 4; ++j) {
            #pragma unroll
            for (int rg = 0; rg < 4; ++rg) {
                int r = m0 + wrow * 64 + i * 16 + q4 + rg;
                int c = n0 + wcol * 64 + j * 16 + ml;
                C[(size_t)r * HF + c] = f2bf(acc[i][j][rg]);
            }
        }
    }
}

// ---------- fused CSR gather + self-loop + bias + BN + ReLU (R2 body) ----------
// one wave per node; 2 edges per gather instruction (lane halves), 8 feats/lane.
#define AGBL 8   // loads per main batch; each load covers 2 edges
template<int FINAL>
__global__ void agg_kernel(const unsigned short* __restrict__ h,
                           const int* __restrict__ ptr,
                           const int2* __restrict__ edge,
                           const float* __restrict__ dinv,
                           const float* __restrict__ b, const float* __restrict__ g,
                           const float* __restrict__ be, const float* __restrict__ m,
                           const float* __restrict__ v,
                           unsigned short* __restrict__ out,
                           const float* __restrict__ W3, float* __restrict__ h3, int n) {
    int wid  = (blockIdx.x * blockDim.x + threadIdx.x) >> 6;
    int lane = threadIdx.x & 63;
    if (wid >= n) return;
    const int hi = lane >> 5;          // which edge of the pair this half handles
    const int l  = lane & 31;
    const int fo = l * 8;              // 8 features per lane (16B)

    int p0 = ptr[wid], p1 = ptr[wid + 1];
    int deg = p1 - p0;

    float a0 = 0.f, a1 = 0.f, a2 = 0.f, a3 = 0.f;
    float a4 = 0.f, a5 = 0.f, a6 = 0.f, a7 = 0.f;

    // ---- main: batches of 16 edges (8 paired loads) ----
    const int nb = deg & ~15;
    for (int t = 0; t < nb; t += 16) {
        int2 ed[AGBL];
        #pragma unroll
        for (int k = 0; k < AGBL; ++k) ed[k] = edge[p0 + t + 2 * k + hi];
        u16x8 hv[AGBL];
        #pragma unroll
        for (int k = 0; k < AGBL; ++k)
            hv[k] = *(const u16x8*)(h + (size_t)(unsigned)ed[k].x * HF + fo);
        #pragma unroll
        for (int k = 0; k < AGBL; ++k) {
            float nw = __int_as_float(ed[k].y);
            a0 += nw * bf2f(hv[k][0]);
            a1 += nw * bf2f(hv[k][1]);
            a2 += nw * bf2f(hv[k][2]);
            a3 += nw * bf2f(hv[k][3]);
            a4 += nw * bf2f(hv[k][4]);
            a5 += nw * bf2f(hv[k][5]);
            a6 += nw * bf2f(hv[k][6]);
            a7 += nw * bf2f(hv[k][7]);
        }
    }
    // ---- tail: 4-edge clamped steps (2 paired loads) ----
    for (int t = nb; t < deg; t += 4) {
        int2 ed[2];
        float wv2[2];
        #pragma unroll
        for (int j = 0; j < 2; ++j) {
            int idx = t + 2 * j + hi;
            int cl = idx < deg ? idx : 0;     // deg >= 1 here, edge[p0] valid
            ed[j] = edge[p0 + cl];
            wv2[j] = (idx < deg) ? __int_as_float(ed[j].y) : 0.0f;
        }
        u16x8 hv[2];
        #pragma unroll
        for (int j = 0; j < 2; ++j)
            hv[j] = *(const u16x8*)(h + (size_t)(unsigned)ed[j].x * HF + fo);
        #pragma unroll
        for (int j = 0; j < 2; ++j) {
            float nw = wv2[j];
            a0 += nw * bf2f(hv[j][0]);
            a1 += nw * bf2f(hv[j][1]);
            a2 += nw * bf2f(hv[j][2]);
            a3 += nw * bf2f(hv[j][3]);
            a4 += nw * bf2f(hv[j][4]);
            a5 += nw * bf2f(hv[j][5]);
            a6 += nw * bf2f(hv[j][6]);
            a7 += nw * bf2f(hv[j][7]);
        }
    }

    // combine the two halves (lanes l and l+32 hold same features, different edges)
    a0 += __shfl_xor(a0, 32, 64);
    a1 += __shfl_xor(a1, 32, 64);
    a2 += __shfl_xor(a2, 32, 64);
    a3 += __shfl_xor(a3, 32, 64);
    a4 += __shfl_xor(a4, 32, 64);
    a5 += __shfl_xor(a5, 32, 64);
    a6 += __shfl_xor(a6, 32, 64);
    a7 += __shfl_xor(a7, 32, 64);

    // self loop: weight 1, norm = dinv^2 (all lanes hold identical totals now)
    float s = dinv[wid];
    float sl = s * s;
    u16x8 hs = *(const u16x8*)(h + (size_t)wid * HF + fo);
    a0 += sl * bf2f(hs[0]);
    a1 += sl * bf2f(hs[1]);
    a2 += sl * bf2f(hs[2]);
    a3 += sl * bf2f(hs[3]);
    a4 += sl * bf2f(hs[4]);
    a5 += sl * bf2f(hs[5]);
    a6 += sl * bf2f(hs[6]);
    a7 += sl * bf2f(hs[7]);

    float4 bb0  = *(const float4*)(b + fo),      bb1  = *(const float4*)(b + fo + 4);
    float4 gg0  = *(const float4*)(g + fo),      gg1  = *(const float4*)(g + fo + 4);
    float4 bee0 = *(const float4*)(be + fo),     bee1 = *(const float4*)(be + fo + 4);
    float4 mm0  = *(const float4*)(m + fo),      mm1  = *(const float4*)(m + fo + 4);
    float4 vv0  = *(const float4*)(v + fo),      vv1  = *(const float4*)(v + fo + 4);
    float f0 = fmaxf((a0 + bb0.x - mm0.x) * rsqrtf(vv0.x + BN_EPS) * gg0.x + bee0.x, 0.f);
    float f1 = fmaxf((a1 + bb0.y - mm0.y) * rsqrtf(vv0.y + BN_EPS) * gg0.y + bee0.y, 0.f);
    float f2 = fmaxf((a2 + bb0.z - mm0.z) * rsqrtf(vv0.z + BN_EPS) * gg0.z + bee0.z, 0.f);
    float f3 = fmaxf((a3 + bb0.w - mm0.w) * rsqrtf(vv0.w + BN_EPS) * gg0.w + bee0.w, 0.f);
    float f4 = fmaxf((a4 + bb1.x - mm1.x) * rsqrtf(vv1.x + BN_EPS) * gg1.x + bee1.x, 0.f);
    float f5 = fmaxf((a5 + bb1.y - mm1.y) * rsqrtf(vv1.y + BN_EPS) * gg1.y + bee1.y, 0.f);
    float f6 = fmaxf((a6 + bb1.z - mm1.z) * rsqrtf(vv1.z + BN_EPS) * gg1.z + bee1.z, 0.f);
    float f7 = fmaxf((a7 + bb1.w - mm1.w) * rsqrtf(vv1.w + BN_EPS) * gg1.w + bee1.w, 0.f);

    if (!FINAL) {
        if (hi == 0) {                     // lanes 0..31 cover all 256 feats
            u16x8 o;
            o[0] = f2bf(f0); o[1] = f2bf(f1); o[2] = f2bf(f2); o[3] = f2bf(f3);
            o[4] = f2bf(f4); o[5] = f2bf(f5); o[6] = f2bf(f6); o[7] = f2bf(f7);
            *(u16x8*)(out + (size_t)wid * HF + fo) = o;
        }
    } else {
        // fused layer-3 GEMV: h3[wid, o] = sum_f act[f] * W3[f][o]
        float4 w0 = *(const float4*)(W3 + fo * 2);
        float4 w1 = *(const float4*)(W3 + fo * 2 + 4);
        float4 w2 = *(const float4*)(W3 + fo * 2 + 8);
        float4 w3 = *(const float4*)(W3 + fo * 2 + 12);
        float s0 = f0 * w0.x + f1 * w0.z + f2 * w1.x + f3 * w1.z
                 + f4 * w2.x + f5 * w2.z + f6 * w3.x + f7 * w3.z;
        float s1 = f0 * w0.y + f1 * w0.w + f2 * w1.y + f3 * w1.w
                 + f4 * w2.y + f5 * w2.w + f6 * w3.y + f7 * w3.w;
        // halves hold identical values; reduce within the 32-lane half
        #pragma unroll
        for (int o = 16; o > 0; o >>= 1) {
            s0 += __shfl_xor(s0, o, 64);
            s1 += __shfl_xor(s1, o, 64);
        }
        if (lane == 0) {
            h3[wid * 2 + 0] = s0;
            h3[wid * 2 + 1] = s1;
        }
    }
}

// ---------- final: CSR gather (2 features) + self-loop + bias ----------
__global__ void out_kernel(const float* __restrict__ h3,
                           const int* __restrict__ ptr, const int2* __restrict__ edge,
                           const float* __restrict__ dinv,
                           const float* __restrict__ b3, float* __restrict__ out, int n) {
    int i = blockIdx.x * blockDim.x + threadIdx.x;
    if (i >= n) return;
    int p0 = ptr[i], p1 = ptr[i + 1];
    float a0 = 0.f, a1 = 0.f;
    for (int p = p0; p < p1; p += 4) {
        #pragma unroll
        for (int k = 0; k < 4; ++k) {
            int idx = p + k < p1 ? p + k : p1 - 1;
            int2 e = edge[idx];
            float nw = (p + k < p1) ? __int_as_float(e.y) : 0.0f;
            float2 u = *(const float2*)(h3 + 2 * e.x);
            a0 += nw * u.x;
            a1 += nw * u.y;
        }
    }
    float s = dinv[i];
    float sl = s * s;
    out[2 * i + 0] = a0 + sl * h3[2 * i + 0] + b3[0];
    out[2 * i + 1] = a1 + sl * h3[2 * i + 1] + b3[1];
}

static inline char* align16(char* p) {
    return (char*)(((uintptr_t)p + 15) & ~(uintptr_t)15);
}

extern "C" void kernel_launch(void* const* d_in, const int* in_sizes, int n_in,
                              void* d_out, int out_size, void* d_ws, size_t ws_size,
                              hipStream_t stream) {
    const float* x   = (const float*)d_in[0];
    const int*   ei  = (const int*)d_in[1];    // int64 in reference -> int32 in harness
    const float* ew  = (const float*)d_in[2];
    const float* W1  = (const float*)d_in[3];
    const float* b1  = (const float*)d_in[4];
    const float* g1  = (const float*)d_in[5];
    const float* be1 = (const float*)d_in[6];
    const float* m1  = (const float*)d_in[7];
    const float* v1  = (const float*)d_in[8];
    const float* W2  = (const float*)d_in[9];
    const float* b2  = (const float*)d_in[10];
    const float* g2  = (const float*)d_in[11];
    const float* be2 = (const float*)d_in[12];
    const float* m2  = (const float*)d_in[13];
    const float* v2  = (const float*)d_in[14];
    const float* W3  = (const float*)d_in[15];
    const float* b3  = (const float*)d_in[16];

    const int N  = in_sizes[0] / F_IN;         // 50000
    const int E  = in_sizes[2];                // 800000
    const int MP = (N + 127) & ~127;           // 50048
    const int* row = ei;
    const int* col = ei + E;

    char* wsb = (char*)d_ws;
    unsigned long long* packed = (unsigned long long*)wsb; wsb = align16(wsb + (size_t)N * 8);
    float* dinv     = (float*)wsb;          wsb = align16(wsb + (size_t)N * 4);
    int*   csr_ptr  = (int*)wsb;            wsb = align16(wsb + (size_t)(N + 1) * 4);
    int*   cursor   = (int*)wsb;            wsb = align16(wsb + (size_t)N * 4);
    int*   blocksum = (int*)wsb;            wsb = align16(wsb + (size_t)SCAN_B * 4);
    int2*  csr_edge = (int2*)wsb;           wsb = align16(wsb + (size_t)E * 8);
    unsigned short* W1t = (unsigned short*)wsb;  wsb = align16(wsb + (size_t)F_IN * HF * 2);
    unsigned short* W2t = (unsigned short*)wsb;  wsb = align16(wsb + (size_t)HF * HF * 2);
    unsigned short* xbf  = (unsigned short*)wsb; wsb = align16(wsb + (size_t)MP * F_IN * 2);
    unsigned short* bufh = (unsigned short*)wsb; wsb = align16(wsb + (size_t)MP * HF * 2);
    unsigned short* bufa = (unsigned short*)wsb; wsb = align16(wsb + (size_t)MP * HF * 2);
    float* h3 = (float*)wsb;                wsb = align16(wsb + (size_t)N * OUT_F * 4);
    int*   bar = (int*)wsb;                 wsb = align16(wsb + 2 * 4);
    float* outf = (float*)d_out;

    const int TB = 256;
    const int nscan = (N + SCAN_B - 1) / SCAN_B;        // 196
    const int padx = (MP - N) * F_IN;
    const int pada = (MP - N) * HF;
    const int nchunk = (N * F_IN) / 8;                  // 3.2M bf16x8 chunks

    // --- barrier state must start at zero (workspace may be poisoned) ---
    (void)hipMemsetAsync(bar, 0, 2 * sizeof(int), stream);

    // --- fused front-end: prep + xconv + count + scan1 + scan3 + fill ---
    setup_kernel<<<NBSETUP, TB, 0, stream>>>(
        packed, W1, W1t, W2, W2t, xbf, bufa, x, row, col, ew,
        csr_ptr, cursor, blocksum, dinv, csr_edge, bar,
        N, E, padx, pada, nscan, nchunk);

    dim3 ggrid(MP / 128, HF / 128);   // (391, 2)

    // --- layer 1 ---
    gemm_kernel<<<ggrid, TB, 0, stream>>>(xbf, W1t, bufh, F_IN);
    agg_kernel<0><<<((size_t)N * 64 + TB - 1) / TB, TB, 0, stream>>>(
        bufh, csr_ptr, csr_edge, dinv, b1, g1, be1, m1, v1, bufa, nullptr, nullptr, N);

    // --- layer 2 ---
    gemm_kernel<<<ggrid, TB, 0, stream>>>(bufa, W2t, bufh, HF);
    agg_kernel<1><<<((size_t)N * 64 + TB - 1) / TB, TB, 0, stream>>>(
        bufh, csr_ptr, csr_edge, dinv, b2, g2, be2, m2, v2, nullptr, W3, h3, N);

    // --- final 2-feature aggregation ---
    out_kernel<<<(N + TB - 1) / TB, TB, 0, stream>>>(h3, csr_ptr, csr_edge, dinv, b3, outf, N);
}

// Round 7
// 518.150 us; speedup vs baseline: 1.7799x; 1.7799x over previous
//
#include <hip/hip_runtime.h>
#include <stdint.h>

#define F_IN 512
#define HF 256
#define OUT_F 2
#define BN_EPS 1e-5f
#define SCAN_B 256
#define LDSTR 36    // LDS row stride (shorts): 0 bank conflicts (measured R7 prev session)

typedef __attribute__((ext_vector_type(8))) short bf16x8;
typedef __attribute__((ext_vector_type(8))) unsigned short u16x8;
typedef __attribute__((ext_vector_type(4))) float f32x4;

__device__ inline float bf2f(unsigned short u) {
    union { float f; uint32_t i; } v; v.i = ((uint32_t)u) << 16; return v.f;
}
__device__ inline unsigned short f2bf(float f) {
    union { float f; uint32_t i; } v; v.f = f;
    uint32_t r = v.i + 0x7FFFu + ((v.i >> 16) & 1u);   // RNE (finite values only)
    return (unsigned short)(r >> 16);
}

// ---------- front: W transposes + pad zeroing + x->bf16 + degree count ----------
// packed[] pre-zeroed by hipMemsetAsync; self-loop folded into scan3's deg (integer
// domain, bit-identical). All loops touch disjoint data -> no ordering needed.
__global__ void front_kernel(unsigned long long* __restrict__ packed,
                             const float* __restrict__ W1, unsigned short* __restrict__ W1t,
                             const float* __restrict__ W2, unsigned short* __restrict__ W2t,
                             const float* __restrict__ x, unsigned short* __restrict__ xbf,
                             unsigned short* __restrict__ bufa_pad,
                             const int* __restrict__ col, const float* __restrict__ ew,
                             int n, int e, int padx, int pada, int nchunk) {
    const int gsz  = gridDim.x * blockDim.x;
    const int gtid = blockIdx.x * blockDim.x + threadIdx.x;

    // degree count (packed 64-bit atomics; count in bits >=40, weight sum in low 40)
    for (int i = gtid; i < e; i += gsz) {
        unsigned long long add = (1ULL << 40)
            | (unsigned long long)__float2uint_rn(ew[i] * 1048576.0f);
        atomicAdd(&packed[col[i]], add);
    }
    // weight transposes
    for (int j = gtid; j < F_IN * HF; j += gsz) {
        int nn = j >> 9, k = j & (F_IN - 1);
        W1t[j] = f2bf(W1[(size_t)k * HF + nn]);
    }
    for (int j = gtid; j < HF * HF; j += gsz) {
        int nn = j >> 8, k = j & (HF - 1);
        W2t[j] = f2bf(W2[(size_t)k * HF + nn]);
    }
    // pad rows
    for (int j = gtid; j < padx; j += gsz) xbf[(size_t)n * F_IN + j] = 0;
    for (int j = gtid; j < pada; j += gsz) bufa_pad[j] = 0;
    // x -> bf16 (8 elems/chunk)
    const float4* x4 = (const float4*)x;
    for (int c = gtid; c < nchunk; c += gsz) {
        float4 f0 = x4[2 * c];
        float4 f1 = x4[2 * c + 1];
        bf16x8 v;
        v[0] = (short)f2bf(f0.x); v[1] = (short)f2bf(f0.y);
        v[2] = (short)f2bf(f0.z); v[3] = (short)f2bf(f0.w);
        v[4] = (short)f2bf(f1.x); v[5] = (short)f2bf(f1.y);
        v[6] = (short)f2bf(f1.z); v[7] = (short)f2bf(f1.w);
        *(bf16x8*)(xbf + (size_t)c * 8) = v;
    }
}

// ---------- scan1: block-local exclusive scan of counts ----------
__global__ void scan1_kernel(const unsigned long long* __restrict__ packed,
                             int* __restrict__ local, int* __restrict__ blocksum, int n) {
    __shared__ int tmp[SCAN_B];
    int i = blockIdx.x * SCAN_B + threadIdx.x;
    int v = (i < n) ? (int)(packed[i] >> 40) : 0;
    tmp[threadIdx.x] = v;
    __syncthreads();
    for (int off = 1; off < SCAN_B; off <<= 1) {
        int t = 0;
        if ((int)threadIdx.x >= off) t = tmp[threadIdx.x - off];
        __syncthreads();
        if ((int)threadIdx.x >= off) tmp[threadIdx.x] += t;
        __syncthreads();
    }
    if (i < n) local[i] = tmp[threadIdx.x] - v;       // exclusive
    if (threadIdx.x == SCAN_B - 1) blocksum[blockIdx.x] = tmp[SCAN_B - 1];
}

// ---------- scan3: add block prefix + dinv (self-loop added in INTEGER domain) ----------
__global__ void scan3_dinv_kernel(int* __restrict__ csr_ptr, int* __restrict__ cursor,
                                  const int* __restrict__ blocksum,
                                  const unsigned long long* __restrict__ packed,
                                  float* __restrict__ dinv, int n, int e, int nb) {
    __shared__ int red[SCAN_B];
    int t = threadIdx.x;
    red[t] = (t < nb && t < (int)blockIdx.x) ? blocksum[t] : 0;
    __syncthreads();
    for (int off = SCAN_B / 2; off > 0; off >>= 1) {
        if (t < off) red[t] += red[t + off];
        __syncthreads();
    }
    int prefix = red[0];
    int i = blockIdx.x * SCAN_B + t;
    if (i < n) {
        int val = csr_ptr[i] + prefix;
        csr_ptr[i] = val;
        cursor[i] = val;
        // + (1<<20) = self-loop weight 1.0 in 24.20 fixpoint (bit-identical to seeded init)
        float deg = (float)((packed[i] & 0xFFFFFFFFFFULL) + (1ULL << 20)) * (1.0f / 1048576.0f);
        dinv[i] = rsqrtf(deg);
    }
    if (i == 0) csr_ptr[n] = e;
}

// ---------- m204 bijective XCD swizzle over ngemm blocks (round-robin blk->XCD) ----------
__device__ inline int xcd_swizzle(int orig, int ngemm) {
    int xcd = orig & 7, j = orig >> 3;
    int q = ngemm >> 3, r8 = ngemm & 7;
    return (xcd < r8 ? xcd * (q + 1) : r8 * (q + 1) + (xcd - r8) * q) + j;
}

// ---------- gemm body (shared by fillgemm and gemm2): 128x128 tile, swizzled ----------
__device__ inline void gemm_body(const unsigned short* __restrict__ A,
                                 const unsigned short* __restrict__ Bt,
                                 unsigned short* __restrict__ C, int K,
                                 int m0, int n0,
                                 unsigned short (*As)[128 * LDSTR],
                                 unsigned short (*Bs)[128 * LDSTR]) {
    const int tid  = threadIdx.x;
    const int lane = tid & 63;
    const int wv   = tid >> 6;
    const int wrow = wv >> 1, wcol = wv & 1;

    const int sr = tid >> 2;          // staging row 0..63
    const int sc = (tid & 3) * 8;     // staging k-offset 0,8,16,24

    const unsigned short* pa0 = A + (size_t)(m0 + sr) * K + sc;
    const unsigned short* pa1 = A + (size_t)(m0 + sr + 64) * K + sc;
    const unsigned short* pb0 = Bt + (size_t)(n0 + sr) * K + sc;
    const unsigned short* pb1 = Bt + (size_t)(n0 + sr + 64) * K + sc;

    f32x4 zero4 = {0.0f, 0.0f, 0.0f, 0.0f};
    f32x4 acc[4][4];
    #pragma unroll
    for (int i = 0; i < 4; ++i)
        #pragma unroll
        for (int j = 0; j < 4; ++j) acc[i][j] = zero4;

    const int q8 = (lane >> 4) * 8;
    const int ml = lane & 15;

    bf16x8 va0 = *(const bf16x8*)pa0;
    bf16x8 va1 = *(const bf16x8*)pa1;
    bf16x8 vb0 = *(const bf16x8*)pb0;
    bf16x8 vb1 = *(const bf16x8*)pb1;

    const int nsteps = K >> 5;
    for (int s = 0; s < nsteps; ++s) {
        const int buf = s & 1;
        *(bf16x8*)&As[buf][sr * LDSTR + sc]        = va0;
        *(bf16x8*)&As[buf][(sr + 64) * LDSTR + sc] = va1;
        *(bf16x8*)&Bs[buf][sr * LDSTR + sc]        = vb0;
        *(bf16x8*)&Bs[buf][(sr + 64) * LDSTR + sc] = vb1;
        __syncthreads();
        if (s + 1 < nsteps) {             // prefetch next tile
            int off = (s + 1) * 32;
            va0 = *(const bf16x8*)(pa0 + off);
            va1 = *(const bf16x8*)(pa1 + off);
            vb0 = *(const bf16x8*)(pb0 + off);
            vb1 = *(const bf16x8*)(pb1 + off);
        }
        bf16x8 af[4], bfr[4];
        #pragma unroll
        for (int i = 0; i < 4; ++i)
            af[i] = *(const bf16x8*)&As[buf][(wrow * 64 + i * 16 + ml) * LDSTR + q8];
        #pragma unroll
        for (int j = 0; j < 4; ++j)
            bfr[j] = *(const bf16x8*)&Bs[buf][(wcol * 64 + j * 16 + ml) * LDSTR + q8];
        #pragma unroll
        for (int i = 0; i < 4; ++i)
            #pragma unroll
            for (int j = 0; j < 4; ++j)
                acc[i][j] = __builtin_amdgcn_mfma_f32_16x16x32_bf16(af[i], bfr[j], acc[i][j], 0, 0, 0);
    }

    // C store (bf16): col=lane&15, row=(lane>>4)*4+reg
    const int q4 = (lane >> 4) * 4;
    #pragma unroll
    for (int i = 0; i < 4; ++i) {
        #pragma unroll
        for (int j = 0; j < 4; ++j) {
            #pragma unroll
            for (int rg = 0; rg < 4; ++rg) {
                int r = m0 + wrow * 64 + i * 16 + q4 + rg;
                int c = n0 + wcol * 64 + j * 16 + ml;
                C[(size_t)r * HF + c] = f2bf(acc[i][j][rg]);
            }
        }
    }
}

// ---------- fused: gemm1 blocks [0,ngemm) + CSR fill blocks [ngemm, ...) ----------
// Independent data (fill writes csr_edge; gemm reads xbf/W1t) -> no sync needed.
// gemm blocks first (long pole starts immediately); fill hides underneath.
__global__ __launch_bounds__(256)
void fillgemm_kernel(const unsigned short* __restrict__ A,
                     const unsigned short* __restrict__ Bt,
                     unsigned short* __restrict__ C, int K, int ngemm,
                     const int* __restrict__ row, const int* __restrict__ col,
                     const float* __restrict__ w, const float* __restrict__ dinv,
                     int* __restrict__ cursor, int2* __restrict__ csr_edge, int e) {
    __shared__ unsigned short As[2][128 * LDSTR];
    __shared__ unsigned short Bs[2][128 * LDSTR];
    if ((int)blockIdx.x >= ngemm) {       // ---- fill path ----
        int i = ((int)blockIdx.x - ngemm) * blockDim.x + threadIdx.x;
        if (i < e) {
            int r = row[i], c = col[i];
            int pos = atomicAdd(&cursor[c], 1);
            float nrm = dinv[r] * w[i] * dinv[c];
            csr_edge[pos] = make_int2(r, __float_as_int(nrm));
        }
        return;
    }
    // ---- gemm path (XCD-swizzled: n-pair of one m-tile lands on one XCD) ----
    int logical = xcd_swizzle(blockIdx.x, ngemm);
    gemm_body(A, Bt, C, K, (logical >> 1) * 128, (logical & 1) * 128, As, Bs);
}

// ---------- standalone gemm (layer 2), same swizzle ----------
__global__ __launch_bounds__(256)
void gemm_kernel(const unsigned short* __restrict__ A,
                 const unsigned short* __restrict__ Bt,
                 unsigned short* __restrict__ C, int K, int ngemm) {
    __shared__ unsigned short As[2][128 * LDSTR];
    __shared__ unsigned short Bs[2][128 * LDSTR];
    int logical = xcd_swizzle(blockIdx.x, ngemm);
    gemm_body(A, Bt, C, K, (logical >> 1) * 128, (logical & 1) * 128, As, Bs);
}

// ---------- fused CSR gather + self-loop + bias + BN + ReLU (R2 body) ----------
// one wave per node; 2 edges per gather instruction (lane halves), 8 feats/lane.
#define AGBL 8   // loads per main batch; each load covers 2 edges
template<int FINAL>
__global__ void agg_kernel(const unsigned short* __restrict__ h,
                           const int* __restrict__ ptr,
                           const int2* __restrict__ edge,
                           const float* __restrict__ dinv,
                           const float* __restrict__ b, const float* __restrict__ g,
                           const float* __restrict__ be, const float* __restrict__ m,
                           const float* __restrict__ v,
                           unsigned short* __restrict__ out,
                           const float* __restrict__ W3, float* __restrict__ h3, int n) {
    int wid  = (blockIdx.x * blockDim.x + threadIdx.x) >> 6;
    int lane = threadIdx.x & 63;
    if (wid >= n) return;
    const int hi = lane >> 5;          // which edge of the pair this half handles
    const int l  = lane & 31;
    const int fo = l * 8;              // 8 features per lane (16B)

    int p0 = ptr[wid], p1 = ptr[wid + 1];
    int deg = p1 - p0;

    float a0 = 0.f, a1 = 0.f, a2 = 0.f, a3 = 0.f;
    float a4 = 0.f, a5 = 0.f, a6 = 0.f, a7 = 0.f;

    // ---- main: batches of 16 edges (8 paired loads) ----
    const int nb = deg & ~15;
    for (int t = 0; t < nb; t += 16) {
        int2 ed[AGBL];
        #pragma unroll
        for (int k = 0; k < AGBL; ++k) ed[k] = edge[p0 + t + 2 * k + hi];
        u16x8 hv[AGBL];
        #pragma unroll
        for (int k = 0; k < AGBL; ++k)
            hv[k] = *(const u16x8*)(h + (size_t)(unsigned)ed[k].x * HF + fo);
        #pragma unroll
        for (int k = 0; k < AGBL; ++k) {
            float nw = __int_as_float(ed[k].y);
            a0 += nw * bf2f(hv[k][0]);
            a1 += nw * bf2f(hv[k][1]);
            a2 += nw * bf2f(hv[k][2]);
            a3 += nw * bf2f(hv[k][3]);
            a4 += nw * bf2f(hv[k][4]);
            a5 += nw * bf2f(hv[k][5]);
            a6 += nw * bf2f(hv[k][6]);
            a7 += nw * bf2f(hv[k][7]);
        }
    }
    // ---- tail: 4-edge clamped steps (2 paired loads) ----
    for (int t = nb; t < deg; t += 4) {
        int2 ed[2];
        float wv2[2];
        #pragma unroll
        for (int j = 0; j < 2; ++j) {
            int idx = t + 2 * j + hi;
            int cl = idx < deg ? idx : 0;     // deg >= 1 here, edge[p0] valid
            ed[j] = edge[p0 + cl];
            wv2[j] = (idx < deg) ? __int_as_float(ed[j].y) : 0.0f;
        }
        u16x8 hv[2];
        #pragma unroll
        for (int j = 0; j < 2; ++j)
            hv[j] = *(const u16x8*)(h + (size_t)(unsigned)ed[j].x * HF + fo);
        #pragma unroll
        for (int j = 0; j < 2; ++j) {
            float nw = wv2[j];
            a0 += nw * bf2f(hv[j][0]);
            a1 += nw * bf2f(hv[j][1]);
            a2 += nw * bf2f(hv[j][2]);
            a3 += nw * bf2f(hv[j][3]);
            a4 += nw * bf2f(hv[j][4]);
            a5 += nw * bf2f(hv[j][5]);
            a6 += nw * bf2f(hv[j][6]);
            a7 += nw * bf2f(hv[j][7]);
        }
    }

    // combine the two halves (lanes l and l+32 hold same features, different edges)
    a0 += __shfl_xor(a0, 32, 64);
    a1 += __shfl_xor(a1, 32, 64);
    a2 += __shfl_xor(a2, 32, 64);
    a3 += __shfl_xor(a3, 32, 64);
    a4 += __shfl_xor(a4, 32, 64);
    a5 += __shfl_xor(a5, 32, 64);
    a6 += __shfl_xor(a6, 32, 64);
    a7 += __shfl_xor(a7, 32, 64);

    // self loop: weight 1, norm = dinv^2 (all lanes hold identical totals now)
    float s = dinv[wid];
    float sl = s * s;
    u16x8 hs = *(const u16x8*)(h + (size_t)wid * HF + fo);
    a0 += sl * bf2f(hs[0]);
    a1 += sl * bf2f(hs[1]);
    a2 += sl * bf2f(hs[2]);
    a3 += sl * bf2f(hs[3]);
    a4 += sl * bf2f(hs[4]);
    a5 += sl * bf2f(hs[5]);
    a6 += sl * bf2f(hs[6]);
    a7 += sl * bf2f(hs[7]);

    float4 bb0  = *(const float4*)(b + fo),      bb1  = *(const float4*)(b + fo + 4);
    float4 gg0  = *(const float4*)(g + fo),      gg1  = *(const float4*)(g + fo + 4);
    float4 bee0 = *(const float4*)(be + fo),     bee1 = *(const float4*)(be + fo + 4);
    float4 mm0  = *(const float4*)(m + fo),      mm1  = *(const float4*)(m + fo + 4);
    float4 vv0  = *(const float4*)(v + fo),      vv1  = *(const float4*)(v + fo + 4);
    float f0 = fmaxf((a0 + bb0.x - mm0.x) * rsqrtf(vv0.x + BN_EPS) * gg0.x + bee0.x, 0.f);
    float f1 = fmaxf((a1 + bb0.y - mm0.y) * rsqrtf(vv0.y + BN_EPS) * gg0.y + bee0.y, 0.f);
    float f2 = fmaxf((a2 + bb0.z - mm0.z) * rsqrtf(vv0.z + BN_EPS) * gg0.z + bee0.z, 0.f);
    float f3 = fmaxf((a3 + bb0.w - mm0.w) * rsqrtf(vv0.w + BN_EPS) * gg0.w + bee0.w, 0.f);
    float f4 = fmaxf((a4 + bb1.x - mm1.x) * rsqrtf(vv1.x + BN_EPS) * gg1.x + bee1.x, 0.f);
    float f5 = fmaxf((a5 + bb1.y - mm1.y) * rsqrtf(vv1.y + BN_EPS) * gg1.y + bee1.y, 0.f);
    float f6 = fmaxf((a6 + bb1.z - mm1.z) * rsqrtf(vv1.z + BN_EPS) * gg1.z + bee1.z, 0.f);
    float f7 = fmaxf((a7 + bb1.w - mm1.w) * rsqrtf(vv1.w + BN_EPS) * gg1.w + bee1.w, 0.f);

    if (!FINAL) {
        if (hi == 0) {                     // lanes 0..31 cover all 256 feats
            u16x8 o;
            o[0] = f2bf(f0); o[1] = f2bf(f1); o[2] = f2bf(f2); o[3] = f2bf(f3);
            o[4] = f2bf(f4); o[5] = f2bf(f5); o[6] = f2bf(f6); o[7] = f2bf(f7);
            *(u16x8*)(out + (size_t)wid * HF + fo) = o;
        }
    } else {
        // fused layer-3 GEMV: h3[wid, o] = sum_f act[f] * W3[f][o]
        float4 w0 = *(const float4*)(W3 + fo * 2);
        float4 w1 = *(const float4*)(W3 + fo * 2 + 4);
        float4 w2 = *(const float4*)(W3 + fo * 2 + 8);
        float4 w3 = *(const float4*)(W3 + fo * 2 + 12);
        float s0 = f0 * w0.x + f1 * w0.z + f2 * w1.x + f3 * w1.z
                 + f4 * w2.x + f5 * w2.z + f6 * w3.x + f7 * w3.z;
        float s1 = f0 * w0.y + f1 * w0.w + f2 * w1.y + f3 * w1.w
                 + f4 * w2.y + f5 * w2.w + f6 * w3.y + f7 * w3.w;
        // halves hold identical values; reduce within the 32-lane half
        #pragma unroll
        for (int o = 16; o > 0; o >>= 1) {
            s0 += __shfl_xor(s0, o, 64);
            s1 += __shfl_xor(s1, o, 64);
        }
        if (lane == 0) {
            h3[wid * 2 + 0] = s0;
            h3[wid * 2 + 1] = s1;
        }
    }
}

// ---------- final: CSR gather (2 features) + self-loop + bias ----------
__global__ void out_kernel(const float* __restrict__ h3,
                           const int* __restrict__ ptr, const int2* __restrict__ edge,
                           const float* __restrict__ dinv,
                           const float* __restrict__ b3, float* __restrict__ out, int n) {
    int i = blockIdx.x * blockDim.x + threadIdx.x;
    if (i >= n) return;
    int p0 = ptr[i], p1 = ptr[i + 1];
    float a0 = 0.f, a1 = 0.f;
    for (int p = p0; p < p1; p += 4) {
        #pragma unroll
        for (int k = 0; k < 4; ++k) {
            int idx = p + k < p1 ? p + k : p1 - 1;
            int2 e = edge[idx];
            float nw = (p + k < p1) ? __int_as_float(e.y) : 0.0f;
            float2 u = *(const float2*)(h3 + 2 * e.x);
            a0 += nw * u.x;
            a1 += nw * u.y;
        }
    }
    float s = dinv[i];
    float sl = s * s;
    out[2 * i + 0] = a0 + sl * h3[2 * i + 0] + b3[0];
    out[2 * i + 1] = a1 + sl * h3[2 * i + 1] + b3[1];
}

static inline char* align16(char* p) {
    return (char*)(((uintptr_t)p + 15) & ~(uintptr_t)15);
}

extern "C" void kernel_launch(void* const* d_in, const int* in_sizes, int n_in,
                              void* d_out, int out_size, void* d_ws, size_t ws_size,
                              hipStream_t stream) {
    const float* x   = (const float*)d_in[0];
    const int*   ei  = (const int*)d_in[1];    // int64 in reference -> int32 in harness
    const float* ew  = (const float*)d_in[2];
    const float* W1  = (const float*)d_in[3];
    const float* b1  = (const float*)d_in[4];
    const float* g1  = (const float*)d_in[5];
    const float* be1 = (const float*)d_in[6];
    const float* m1  = (const float*)d_in[7];
    const float* v1  = (const float*)d_in[8];
    const float* W2  = (const float*)d_in[9];
    const float* b2  = (const float*)d_in[10];
    const float* g2  = (const float*)d_in[11];
    const float* be2 = (const float*)d_in[12];
    const float* m2  = (const float*)d_in[13];
    const float* v2  = (const float*)d_in[14];
    const float* W3  = (const float*)d_in[15];
    const float* b3  = (const float*)d_in[16];

    const int N  = in_sizes[0] / F_IN;         // 50000
    const int E  = in_sizes[2];                // 800000
    const int MP = (N + 127) & ~127;           // 50048
    const int* row = ei;
    const int* col = ei + E;

    char* wsb = (char*)d_ws;
    unsigned long long* packed = (unsigned long long*)wsb; wsb = align16(wsb + (size_t)N * 8);
    float* dinv     = (float*)wsb;          wsb = align16(wsb + (size_t)N * 4);
    int*   csr_ptr  = (int*)wsb;            wsb = align16(wsb + (size_t)(N + 1) * 4);
    int*   cursor   = (int*)wsb;            wsb = align16(wsb + (size_t)N * 4);
    int*   blocksum = (int*)wsb;            wsb = align16(wsb + (size_t)SCAN_B * 4);
    int2*  csr_edge = (int2*)wsb;           wsb = align16(wsb + (size_t)E * 8);
    unsigned short* W1t = (unsigned short*)wsb;  wsb = align16(wsb + (size_t)F_IN * HF * 2);
    unsigned short* W2t = (unsigned short*)wsb;  wsb = align16(wsb + (size_t)HF * HF * 2);
    unsigned short* xbf  = (unsigned short*)wsb; wsb = align16(wsb + (size_t)MP * F_IN * 2);
    unsigned short* bufh = (unsigned short*)wsb; wsb = align16(wsb + (size_t)MP * HF * 2);
    unsigned short* bufa = (unsigned short*)wsb; wsb = align16(wsb + (size_t)MP * HF * 2);
    float* h3 = (float*)wsb;                wsb = align16(wsb + (size_t)N * OUT_F * 4);
    float* outf = (float*)d_out;

    const int TB = 256;
    const int nscan = (N + SCAN_B - 1) / SCAN_B;        // 196
    const int padx = (MP - N) * F_IN;
    const int pada = (MP - N) * HF;
    const int nchunk = (N * F_IN) / 8;                  // 3.2M bf16x8 chunks
    const int ngemm = (MP / 128) * 2;                   // 782
    const int nfill = (E + TB - 1) / TB;                // 3125

    // --- packed counts start at zero (self-loop folded into scan3) ---
    (void)hipMemsetAsync(packed, 0, (size_t)N * 8, stream);

    // --- front: W transposes + pad zero + x->bf16 + degree count ---
    front_kernel<<<1024, TB, 0, stream>>>(
        packed, W1, W1t, W2, W2t, x, xbf, bufa + (size_t)N * HF,
        col, ew, N, E, padx, pada, nchunk);

    // --- CSR scan ---
    scan1_kernel<<<nscan, SCAN_B, 0, stream>>>(packed, csr_ptr, blocksum, N);
    scan3_dinv_kernel<<<nscan, SCAN_B, 0, stream>>>(csr_ptr, cursor, blocksum, packed, dinv, N, E, nscan);

    // --- layer 1 GEMM (swizzled) + CSR fill, fused in one dispatch ---
    fillgemm_kernel<<<ngemm + nfill, TB, 0, stream>>>(
        xbf, W1t, bufh, F_IN, ngemm, row, col, ew, dinv, cursor, csr_edge, E);

    // --- layer 1 aggregation ---
    agg_kernel<0><<<((size_t)N * 64 + TB - 1) / TB, TB, 0, stream>>>(
        bufh, csr_ptr, csr_edge, dinv, b1, g1, be1, m1, v1, bufa, nullptr, nullptr, N);

    // --- layer 2 ---
    gemm_kernel<<<ngemm, TB, 0, stream>>>(bufa, W2t, bufh, HF, ngemm);
    agg_kernel<1><<<((size_t)N * 64 + TB - 1) / TB, TB, 0, stream>>>(
        bufh, csr_ptr, csr_edge, dinv, b2, g2, be2, m2, v2, nullptr, W3, h3, N);

    // --- final 2-feature aggregation ---
    out_kernel<<<(N + TB - 1) / TB, TB, 0, stream>>>(h3, csr_ptr, csr_edge, dinv, b3, outf, N);
}

// Round 9
// 480.143 us; speedup vs baseline: 1.9208x; 1.0792x over previous
//
#include <hip/hip_runtime.h>
#include <stdint.h>

#define F_IN 512
#define HF 256
#define OUT_F 2
#define BN_EPS 1e-5f
#define SCAN_B 256
#define LDSTR 36    // LDS row stride (shorts): 0 bank conflicts (measured R7 prev session)

typedef __attribute__((ext_vector_type(8))) short bf16x8;
typedef __attribute__((ext_vector_type(8))) unsigned short u16x8;
typedef __attribute__((ext_vector_type(4))) float f32x4;

__device__ inline float bf2f(unsigned short u) {
    union { float f; uint32_t i; } v; v.i = ((uint32_t)u) << 16; return v.f;
}
__device__ inline unsigned short f2bf(float f) {
    union { float f; uint32_t i; } v; v.f = f;
    uint32_t r = v.i + 0x7FFFu + ((v.i >> 16) & 1u);   // RNE (finite values only)
    return (unsigned short)(r >> 16);
}

// ---------- front: W transposes + pad zeroing + x->bf16 + degree count ----------
// packed[] pre-zeroed by hipMemsetAsync; self-loop folded into scan3 (integer domain).
__global__ void front_kernel(unsigned long long* __restrict__ packed,
                             const float* __restrict__ W1, unsigned short* __restrict__ W1t,
                             const float* __restrict__ W2, unsigned short* __restrict__ W2t,
                             const float* __restrict__ x, unsigned short* __restrict__ xbf,
                             unsigned short* __restrict__ bufa_pad,
                             const int* __restrict__ col, const float* __restrict__ ew,
                             int n, int e, int padx, int pada, int nchunk) {
    const int gsz  = gridDim.x * blockDim.x;
    const int gtid = blockIdx.x * blockDim.x + threadIdx.x;

    // degree count (packed 64-bit atomics; count in bits >=40, weight sum in low 40)
    for (int i = gtid; i < e; i += gsz) {
        unsigned long long add = (1ULL << 40)
            | (unsigned long long)__float2uint_rn(ew[i] * 1048576.0f);
        atomicAdd(&packed[col[i]], add);
    }
    // weight transposes
    for (int j = gtid; j < F_IN * HF; j += gsz) {
        int nn = j >> 9, k = j & (F_IN - 1);
        W1t[j] = f2bf(W1[(size_t)k * HF + nn]);
    }
    for (int j = gtid; j < HF * HF; j += gsz) {
        int nn = j >> 8, k = j & (HF - 1);
        W2t[j] = f2bf(W2[(size_t)k * HF + nn]);
    }
    // pad rows
    for (int j = gtid; j < padx; j += gsz) xbf[(size_t)n * F_IN + j] = 0;
    for (int j = gtid; j < pada; j += gsz) bufa_pad[j] = 0;
    // x -> bf16 (8 elems/chunk)
    const float4* x4 = (const float4*)x;
    for (int c = gtid; c < nchunk; c += gsz) {
        float4 f0 = x4[2 * c];
        float4 f1 = x4[2 * c + 1];
        bf16x8 v;
        v[0] = (short)f2bf(f0.x); v[1] = (short)f2bf(f0.y);
        v[2] = (short)f2bf(f0.z); v[3] = (short)f2bf(f0.w);
        v[4] = (short)f2bf(f1.x); v[5] = (short)f2bf(f1.y);
        v[6] = (short)f2bf(f1.z); v[7] = (short)f2bf(f1.w);
        *(bf16x8*)(xbf + (size_t)c * 8) = v;
    }
}

// ---------- scan1: block-local exclusive scan of counts ----------
__global__ void scan1_kernel(const unsigned long long* __restrict__ packed,
                             int* __restrict__ local, int* __restrict__ blocksum, int n) {
    __shared__ int tmp[SCAN_B];
    int i = blockIdx.x * SCAN_B + threadIdx.x;
    int v = (i < n) ? (int)(packed[i] >> 40) : 0;
    tmp[threadIdx.x] = v;
    __syncthreads();
    for (int off = 1; off < SCAN_B; off <<= 1) {
        int t = 0;
        if ((int)threadIdx.x >= off) t = tmp[threadIdx.x - off];
        __syncthreads();
        if ((int)threadIdx.x >= off) tmp[threadIdx.x] += t;
        __syncthreads();
    }
    if (i < n) local[i] = tmp[threadIdx.x] - v;       // exclusive
    if (threadIdx.x == SCAN_B - 1) blocksum[blockIdx.x] = tmp[SCAN_B - 1];
}

// ---------- scan3: add block prefix + dinv (self-loop added in INTEGER domain) ----------
__global__ void scan3_dinv_kernel(int* __restrict__ csr_ptr, int* __restrict__ cursor,
                                  const int* __restrict__ blocksum,
                                  const unsigned long long* __restrict__ packed,
                                  float* __restrict__ dinv, int n, int e, int nb) {
    __shared__ int red[SCAN_B];
    int t = threadIdx.x;
    red[t] = (t < nb && t < (int)blockIdx.x) ? blocksum[t] : 0;
    __syncthreads();
    for (int off = SCAN_B / 2; off > 0; off >>= 1) {
        if (t < off) red[t] += red[t + off];
        __syncthreads();
    }
    int prefix = red[0];
    int i = blockIdx.x * SCAN_B + t;
    if (i < n) {
        int val = csr_ptr[i] + prefix;
        csr_ptr[i] = val;
        cursor[i] = val;
        // + (1<<20) = self-loop weight 1.0 in 24.20 fixpoint (bit-identical to seeded init)
        float deg = (float)((packed[i] & 0xFFFFFFFFFFULL) + (1ULL << 20)) * (1.0f / 1048576.0f);
        dinv[i] = rsqrtf(deg);
    }
    if (i == 0) csr_ptr[n] = e;
}

// ---------- CSR fill: bucket edges by col, fold norm, 8B paired store ----------
__global__ void fill_kernel(const int* __restrict__ row, const int* __restrict__ col,
                            const float* __restrict__ w, const float* __restrict__ dinv,
                            int* __restrict__ cursor, int2* __restrict__ csr_edge, int e) {
    int i = blockIdx.x * blockDim.x + threadIdx.x;
    if (i < e) {
        int r = row[i], c = col[i];
        int pos = atomicAdd(&cursor[c], 1);
        float nrm = dinv[r] * w[i] * dinv[c];
        csr_edge[pos] = make_int2(r, __float_as_int(nrm));
    }
}

// ---------- m204 bijective XCD swizzle (round-robin blk->XCD assumption) ----------
__device__ inline int xcd_swizzle(int orig, int ngemm) {
    int xcd = orig & 7, j = orig >> 3;
    int q = ngemm >> 3, r8 = ngemm & 7;
    return (xcd < r8 ? xcd * (q + 1) : r8 * (q + 1) + (xcd - r8) * q) + j;
}

// ---------- pipelined bf16 GEMM: C[MP,256] = A[MP,K] @ Bt[256,K]^T ----------
// TAG only distinguishes mangled names (layer 1 vs 2) for per-dispatch profiling.
// 1D grid + bijective XCD swizzle: both n-tiles of one m-tile land on one XCD.
template<int TAG>
__global__ __launch_bounds__(256)
void gemm_kernel(const unsigned short* __restrict__ A,
                 const unsigned short* __restrict__ Bt,
                 unsigned short* __restrict__ C, int K, int ngemm) {
    __shared__ unsigned short As[2][128 * LDSTR];
    __shared__ unsigned short Bs[2][128 * LDSTR];
    const int logical = xcd_swizzle(blockIdx.x, ngemm);
    const int m0 = (logical >> 1) * 128;
    const int n0 = (logical & 1) * 128;

    const int tid  = threadIdx.x;
    const int lane = tid & 63;
    const int wv   = tid >> 6;
    const int wrow = wv >> 1, wcol = wv & 1;

    const int sr = tid >> 2;          // staging row 0..63
    const int sc = (tid & 3) * 8;     // staging k-offset 0,8,16,24

    const unsigned short* pa0 = A + (size_t)(m0 + sr) * K + sc;
    const unsigned short* pa1 = A + (size_t)(m0 + sr + 64) * K + sc;
    const unsigned short* pb0 = Bt + (size_t)(n0 + sr) * K + sc;
    const unsigned short* pb1 = Bt + (size_t)(n0 + sr + 64) * K + sc;

    f32x4 zero4 = {0.0f, 0.0f, 0.0f, 0.0f};
    f32x4 acc[4][4];
    #pragma unroll
    for (int i = 0; i < 4; ++i)
        #pragma unroll
        for (int j = 0; j < 4; ++j) acc[i][j] = zero4;

    const int q8 = (lane >> 4) * 8;
    const int ml = lane & 15;

    bf16x8 va0 = *(const bf16x8*)pa0;
    bf16x8 va1 = *(const bf16x8*)pa1;
    bf16x8 vb0 = *(const bf16x8*)pb0;
    bf16x8 vb1 = *(const bf16x8*)pb1;

    const int nsteps = K >> 5;
    for (int s = 0; s < nsteps; ++s) {
        const int buf = s & 1;
        *(bf16x8*)&As[buf][sr * LDSTR + sc]        = va0;
        *(bf16x8*)&As[buf][(sr + 64) * LDSTR + sc] = va1;
        *(bf16x8*)&Bs[buf][sr * LDSTR + sc]        = vb0;
        *(bf16x8*)&Bs[buf][(sr + 64) * LDSTR + sc] = vb1;
        __syncthreads();
        if (s + 1 < nsteps) {             // prefetch next tile
            int off = (s + 1) * 32;
            va0 = *(const bf16x8*)(pa0 + off);
            va1 = *(const bf16x8*)(pa1 + off);
            vb0 = *(const bf16x8*)(pb0 + off);
            vb1 = *(const bf16x8*)(pb1 + off);
        }
        bf16x8 af[4], bfr[4];
        #pragma unroll
        for (int i = 0; i < 4; ++i)
            af[i] = *(const bf16x8*)&As[buf][(wrow * 64 + i * 16 + ml) * LDSTR + q8];
        #pragma unroll
        for (int j = 0; j < 4; ++j)
            bfr[j] = *(const bf16x8*)&Bs[buf][(wcol * 64 + j * 16 + ml) * LDSTR + q8];
        #pragma unroll
        for (int i = 0; i < 4; ++i)
            #pragma unroll
            for (int j = 0; j < 4; ++j)
                acc[i][j] = __builtin_amdgcn_mfma_f32_16x16x32_bf16(af[i], bfr[j], acc[i][j], 0, 0, 0);
    }

    // C store (bf16): col=lane&15, row=(lane>>4)*4+reg
    const int q4 = (lane >> 4) * 4;
    #pragma unroll
    for (int i = 0; i < 4; ++i) {
        #pragma unroll
        for (int j = 0; j < 4; ++j) {
            #pragma unroll
            for (int rg = 0; rg < 4; ++rg) {
                int r = m0 + wrow * 64 + i * 16 + q4 + rg;
                int c = n0 + wcol * 64 + j * 16 + ml;
                C[(size_t)r * HF + c] = f2bf(acc[i][j][rg]);
            }
        }
    }
}

// ---------- fused CSR gather + self-loop + bias + BN + ReLU (R2 body) ----------
// one wave per node; 2 edges per gather instruction (lane halves), 8 feats/lane.
#define AGBL 8   // loads per main batch; each load covers 2 edges
template<int FINAL>
__global__ void agg_kernel(const unsigned short* __restrict__ h,
                           const int* __restrict__ ptr,
                           const int2* __restrict__ edge,
                           const float* __restrict__ dinv,
                           const float* __restrict__ b, const float* __restrict__ g,
                           const float* __restrict__ be, const float* __restrict__ m,
                           const float* __restrict__ v,
                           unsigned short* __restrict__ out,
                           const float* __restrict__ W3, float* __restrict__ h3, int n) {
    int wid  = (blockIdx.x * blockDim.x + threadIdx.x) >> 6;
    int lane = threadIdx.x & 63;
    if (wid >= n) return;
    const int hi = lane >> 5;          // which edge of the pair this half handles
    const int l  = lane & 31;
    const int fo = l * 8;              // 8 features per lane (16B)

    int p0 = ptr[wid], p1 = ptr[wid + 1];
    int deg = p1 - p0;

    float a0 = 0.f, a1 = 0.f, a2 = 0.f, a3 = 0.f;
    float a4 = 0.f, a5 = 0.f, a6 = 0.f, a7 = 0.f;

    // ---- main: batches of 16 edges (8 paired loads) ----
    const int nb = deg & ~15;
    for (int t = 0; t < nb; t += 16) {
        int2 ed[AGBL];
        #pragma unroll
        for (int k = 0; k < AGBL; ++k) ed[k] = edge[p0 + t + 2 * k + hi];
        u16x8 hv[AGBL];
        #pragma unroll
        for (int k = 0; k < AGBL; ++k)
            hv[k] = *(const u16x8*)(h + (size_t)(unsigned)ed[k].x * HF + fo);
        #pragma unroll
        for (int k = 0; k < AGBL; ++k) {
            float nw = __int_as_float(ed[k].y);
            a0 += nw * bf2f(hv[k][0]);
            a1 += nw * bf2f(hv[k][1]);
            a2 += nw * bf2f(hv[k][2]);
            a3 += nw * bf2f(hv[k][3]);
            a4 += nw * bf2f(hv[k][4]);
            a5 += nw * bf2f(hv[k][5]);
            a6 += nw * bf2f(hv[k][6]);
            a7 += nw * bf2f(hv[k][7]);
        }
    }
    // ---- tail: 4-edge clamped steps (2 paired loads) ----
    for (int t = nb; t < deg; t += 4) {
        int2 ed[2];
        float wv2[2];
        #pragma unroll
        for (int j = 0; j < 2; ++j) {
            int idx = t + 2 * j + hi;
            int cl = idx < deg ? idx : 0;     // deg >= 1 here, edge[p0] valid
            ed[j] = edge[p0 + cl];
            wv2[j] = (idx < deg) ? __int_as_float(ed[j].y) : 0.0f;
        }
        u16x8 hv[2];
        #pragma unroll
        for (int j = 0; j < 2; ++j)
            hv[j] = *(const u16x8*)(h + (size_t)(unsigned)ed[j].x * HF + fo);
        #pragma unroll
        for (int j = 0; j < 2; ++j) {
            float nw = wv2[j];
            a0 += nw * bf2f(hv[j][0]);
            a1 += nw * bf2f(hv[j][1]);
            a2 += nw * bf2f(hv[j][2]);
            a3 += nw * bf2f(hv[j][3]);
            a4 += nw * bf2f(hv[j][4]);
            a5 += nw * bf2f(hv[j][5]);
            a6 += nw * bf2f(hv[j][6]);
            a7 += nw * bf2f(hv[j][7]);
        }
    }

    // combine the two halves (lanes l and l+32 hold same features, different edges)
    a0 += __shfl_xor(a0, 32, 64);
    a1 += __shfl_xor(a1, 32, 64);
    a2 += __shfl_xor(a2, 32, 64);
    a3 += __shfl_xor(a3, 32, 64);
    a4 += __shfl_xor(a4, 32, 64);
    a5 += __shfl_xor(a5, 32, 64);
    a6 += __shfl_xor(a6, 32, 64);
    a7 += __shfl_xor(a7, 32, 64);

    // self loop: weight 1, norm = dinv^2 (all lanes hold identical totals now)
    float s = dinv[wid];
    float sl = s * s;
    u16x8 hs = *(const u16x8*)(h + (size_t)wid * HF + fo);
    a0 += sl * bf2f(hs[0]);
    a1 += sl * bf2f(hs[1]);
    a2 += sl * bf2f(hs[2]);
    a3 += sl * bf2f(hs[3]);
    a4 += sl * bf2f(hs[4]);
    a5 += sl * bf2f(hs[5]);
    a6 += sl * bf2f(hs[6]);
    a7 += sl * bf2f(hs[7]);

    float4 bb0  = *(const float4*)(b + fo),      bb1  = *(const float4*)(b + fo + 4);
    float4 gg0  = *(const float4*)(g + fo),      gg1  = *(const float4*)(g + fo + 4);
    float4 bee0 = *(const float4*)(be + fo),     bee1 = *(const float4*)(be + fo + 4);
    float4 mm0  = *(const float4*)(m + fo),      mm1  = *(const float4*)(m + fo + 4);
    float4 vv0  = *(const float4*)(v + fo),      vv1  = *(const float4*)(v + fo + 4);
    float f0 = fmaxf((a0 + bb0.x - mm0.x) * rsqrtf(vv0.x + BN_EPS) * gg0.x + bee0.x, 0.f);
    float f1 = fmaxf((a1 + bb0.y - mm0.y) * rsqrtf(vv0.y + BN_EPS) * gg0.y + bee0.y, 0.f);
    float f2 = fmaxf((a2 + bb0.z - mm0.z) * rsqrtf(vv0.z + BN_EPS) * gg0.z + bee0.z, 0.f);
    float f3 = fmaxf((a3 + bb0.w - mm0.w) * rsqrtf(vv0.w + BN_EPS) * gg0.w + bee0.w, 0.f);
    float f4 = fmaxf((a4 + bb1.x - mm1.x) * rsqrtf(vv1.x + BN_EPS) * gg1.x + bee1.x, 0.f);
    float f5 = fmaxf((a5 + bb1.y - mm1.y) * rsqrtf(vv1.y + BN_EPS) * gg1.y + bee1.y, 0.f);
    float f6 = fmaxf((a6 + bb1.z - mm1.z) * rsqrtf(vv1.z + BN_EPS) * gg1.z + bee1.z, 0.f);
    float f7 = fmaxf((a7 + bb1.w - mm1.w) * rsqrtf(vv1.w + BN_EPS) * gg1.w + bee1.w, 0.f);

    if (!FINAL) {
        if (hi == 0) {                     // lanes 0..31 cover all 256 feats
            u16x8 o;
            o[0] = f2bf(f0); o[1] = f2bf(f1); o[2] = f2bf(f2); o[3] = f2bf(f3);
            o[4] = f2bf(f4); o[5] = f2bf(f5); o[6] = f2bf(f6); o[7] = f2bf(f7);
            *(u16x8*)(out + (size_t)wid * HF + fo) = o;
        }
    } else {
        // fused layer-3 GEMV: h3[wid, o] = sum_f act[f] * W3[f][o]
        float4 w0 = *(const float4*)(W3 + fo * 2);
        float4 w1 = *(const float4*)(W3 + fo * 2 + 4);
        float4 w2 = *(const float4*)(W3 + fo * 2 + 8);
        float4 w3 = *(const float4*)(W3 + fo * 2 + 12);
        float s0 = f0 * w0.x + f1 * w0.z + f2 * w1.x + f3 * w1.z
                 + f4 * w2.x + f5 * w2.z + f6 * w3.x + f7 * w3.z;
        float s1 = f0 * w0.y + f1 * w0.w + f2 * w1.y + f3 * w1.w
                 + f4 * w2.y + f5 * w2.w + f6 * w3.y + f7 * w3.w;
        // halves hold identical values; reduce within the 32-lane half
        #pragma unroll
        for (int o = 16; o > 0; o >>= 1) {
            s0 += __shfl_xor(s0, o, 64);
            s1 += __shfl_xor(s1, o, 64);
        }
        if (lane == 0) {
            h3[wid * 2 + 0] = s0;
            h3[wid * 2 + 1] = s1;
        }
    }
}

// ---------- final: CSR gather (2 features) + self-loop + bias ----------
__global__ void out_kernel(const float* __restrict__ h3,
                           const int* __restrict__ ptr, const int2* __restrict__ edge,
                           const float* __restrict__ dinv,
                           const float* __restrict__ b3, float* __restrict__ out, int n) {
    int i = blockIdx.x * blockDim.x + threadIdx.x;
    if (i >= n) return;
    int p0 = ptr[i], p1 = ptr[i + 1];
    float a0 = 0.f, a1 = 0.f;
    for (int p = p0; p < p1; p += 4) {
        #pragma unroll
        for (int k = 0; k < 4; ++k) {
            int idx = p + k < p1 ? p + k : p1 - 1;
            int2 e = edge[idx];
            float nw = (p + k < p1) ? __int_as_float(e.y) : 0.0f;
            float2 u = *(const float2*)(h3 + 2 * e.x);
            a0 += nw * u.x;
            a1 += nw * u.y;
        }
    }
    float s = dinv[i];
    float sl = s * s;
    out[2 * i + 0] = a0 + sl * h3[2 * i + 0] + b3[0];
    out[2 * i + 1] = a1 + sl * h3[2 * i + 1] + b3[1];
}

static inline char* align16(char* p) {
    return (char*)(((uintptr_t)p + 15) & ~(uintptr_t)15);
}

extern "C" void kernel_launch(void* const* d_in, const int* in_sizes, int n_in,
                              void* d_out, int out_size, void* d_ws, size_t ws_size,
                              hipStream_t stream) {
    const float* x   = (const float*)d_in[0];
    const int*   ei  = (const int*)d_in[1];    // int64 in reference -> int32 in harness
    const float* ew  = (const float*)d_in[2];
    const float* W1  = (const float*)d_in[3];
    const float* b1  = (const float*)d_in[4];
    const float* g1  = (const float*)d_in[5];
    const float* be1 = (const float*)d_in[6];
    const float* m1  = (const float*)d_in[7];
    const float* v1  = (const float*)d_in[8];
    const float* W2  = (const float*)d_in[9];
    const float* b2  = (const float*)d_in[10];
    const float* g2  = (const float*)d_in[11];
    const float* be2 = (const float*)d_in[12];
    const float* m2  = (const float*)d_in[13];
    const float* v2  = (const float*)d_in[14];
    const float* W3  = (const float*)d_in[15];
    const float* b3  = (const float*)d_in[16];

    const int N  = in_sizes[0] / F_IN;         // 50000
    const int E  = in_sizes[2];                // 800000
    const int MP = (N + 127) & ~127;           // 50048
    const int* row = ei;
    const int* col = ei + E;

    char* wsb = (char*)d_ws;
    unsigned long long* packed = (unsigned long long*)wsb; wsb = align16(wsb + (size_t)N * 8);
    float* dinv     = (float*)wsb;          wsb = align16(wsb + (size_t)N * 4);
    int*   csr_ptr  = (int*)wsb;            wsb = align16(wsb + (size_t)(N + 1) * 4);
    int*   cursor   = (int*)wsb;            wsb = align16(wsb + (size_t)N * 4);
    int*   blocksum = (int*)wsb;            wsb = align16(wsb + (size_t)SCAN_B * 4);
    int2*  csr_edge = (int2*)wsb;           wsb = align16(wsb + (size_t)E * 8);
    unsigned short* W1t = (unsigned short*)wsb;  wsb = align16(wsb + (size_t)F_IN * HF * 2);
    unsigned short* W2t = (unsigned short*)wsb;  wsb = align16(wsb + (size_t)HF * HF * 2);
    unsigned short* xbf  = (unsigned short*)wsb; wsb = align16(wsb + (size_t)MP * F_IN * 2);
    unsigned short* bufh = (unsigned short*)wsb; wsb = align16(wsb + (size_t)MP * HF * 2);
    unsigned short* bufa = (unsigned short*)wsb; wsb = align16(wsb + (size_t)MP * HF * 2);
    float* h3 = (float*)wsb;                wsb = align16(wsb + (size_t)N * OUT_F * 4);
    float* outf = (float*)d_out;

    const int TB = 256;
    const int nscan = (N + SCAN_B - 1) / SCAN_B;        // 196
    const int padx = (MP - N) * F_IN;
    const int pada = (MP - N) * HF;
    const int nchunk = (N * F_IN) / 8;                  // 3.2M bf16x8 chunks
    const int ngemm = (MP / 128) * 2;                   // 782

    // --- packed counts start at zero (self-loop folded into scan3) ---
    (void)hipMemsetAsync(packed, 0, (size_t)N * 8, stream);

    // --- front: W transposes + pad zero + x->bf16 + degree count ---
    front_kernel<<<1024, TB, 0, stream>>>(
        packed, W1, W1t, W2, W2t, x, xbf, bufa + (size_t)N * HF,
        col, ew, N, E, padx, pada, nchunk);

    // --- CSR build ---
    scan1_kernel<<<nscan, SCAN_B, 0, stream>>>(packed, csr_ptr, blocksum, N);
    scan3_dinv_kernel<<<nscan, SCAN_B, 0, stream>>>(csr_ptr, cursor, blocksum, packed, dinv, N, E, nscan);
    fill_kernel<<<(E + TB - 1) / TB, TB, 0, stream>>>(row, col, ew, dinv, cursor, csr_edge, E);

    // --- layer 1 ---
    gemm_kernel<1><<<ngemm, TB, 0, stream>>>(xbf, W1t, bufh, F_IN, ngemm);
    agg_kernel<0><<<((size_t)N * 64 + TB - 1) / TB, TB, 0, stream>>>(
        bufh, csr_ptr, csr_edge, dinv, b1, g1, be1, m1, v1, bufa, nullptr, nullptr, N);

    // --- layer 2 ---
    gemm_kernel<2><<<ngemm, TB, 0, stream>>>(bufa, W2t, bufh, HF, ngemm);
    agg_kernel<1><<<((size_t)N * 64 + TB - 1) / TB, TB, 0, stream>>>(
        bufh, csr_ptr, csr_edge, dinv, b2, g2, be2, m2, v2, nullptr, W3, h3, N);

    // --- final 2-feature aggregation ---
    out_kernel<<<(N + TB - 1) / TB, TB, 0, stream>>>(h3, csr_ptr, csr_edge, dinv, b3, outf, N);
}

// Round 10
// 465.013 us; speedup vs baseline: 1.9833x; 1.0325x over previous
//
#include <hip/hip_runtime.h>
#include <stdint.h>

#define F_IN 512
#define HF 256
#define OUT_F 2
#define BN_EPS 1e-5f
#define SCAN_B 256
#define LDSTR 36    // LDS row stride (shorts): 0 bank conflicts (measured R7 prev session)

typedef __attribute__((ext_vector_type(8))) short bf16x8;
typedef __attribute__((ext_vector_type(8))) unsigned short u16x8;
typedef __attribute__((ext_vector_type(4))) float f32x4;

__device__ inline float bf2f(unsigned short u) {
    union { float f; uint32_t i; } v; v.i = ((uint32_t)u) << 16; return v.f;
}
__device__ inline unsigned short f2bf(float f) {
    union { float f; uint32_t i; } v; v.f = f;
    uint32_t r = v.i + 0x7FFFu + ((v.i >> 16) & 1u);   // RNE (finite values only)
    return (unsigned short)(r >> 16);
}

// ---------- front: x->bf16 (MLP-batched) + W transposes + pads + degree count ----------
// packed[] pre-zeroed by hipMemsetAsync; self-loop folded into scan3 (integer domain).
// R9 postmortem: conversion loop was latency-bound (1 chunk in flight/wave, 16 waves/CU,
// 1.7 TB/s). Fix: 4 chunks batched (8 loads issued before converts) + grid 2048.
__global__ void front_kernel(unsigned long long* __restrict__ packed,
                             const float* __restrict__ W1, unsigned short* __restrict__ W1t,
                             const float* __restrict__ W2, unsigned short* __restrict__ W2t,
                             const float* __restrict__ x, unsigned short* __restrict__ xbf,
                             unsigned short* __restrict__ bufa_pad,
                             const int* __restrict__ col, const float* __restrict__ ew,
                             int n, int e, int padx, int pada, int nchunk) {
    const int gsz  = gridDim.x * blockDim.x;
    const int gtid = blockIdx.x * blockDim.x + threadIdx.x;

    // x -> bf16: batch of 4 chunks, all loads issued before any convert (4x MLP)
    const float4* x4 = (const float4*)x;
    int c = gtid;
    for (; c + 3 * gsz < nchunk; c += 4 * gsz) {
        float4 f[8];
        #pragma unroll
        for (int u = 0; u < 4; ++u) {
            f[2 * u]     = x4[2 * (c + u * gsz)];
            f[2 * u + 1] = x4[2 * (c + u * gsz) + 1];
        }
        #pragma unroll
        for (int u = 0; u < 4; ++u) {
            bf16x8 v;
            v[0] = (short)f2bf(f[2 * u].x); v[1] = (short)f2bf(f[2 * u].y);
            v[2] = (short)f2bf(f[2 * u].z); v[3] = (short)f2bf(f[2 * u].w);
            v[4] = (short)f2bf(f[2 * u + 1].x); v[5] = (short)f2bf(f[2 * u + 1].y);
            v[6] = (short)f2bf(f[2 * u + 1].z); v[7] = (short)f2bf(f[2 * u + 1].w);
            *(bf16x8*)(xbf + (size_t)(c + u * gsz) * 8) = v;
        }
    }
    for (; c < nchunk; c += gsz) {
        float4 f0 = x4[2 * c];
        float4 f1 = x4[2 * c + 1];
        bf16x8 v;
        v[0] = (short)f2bf(f0.x); v[1] = (short)f2bf(f0.y);
        v[2] = (short)f2bf(f0.z); v[3] = (short)f2bf(f0.w);
        v[4] = (short)f2bf(f1.x); v[5] = (short)f2bf(f1.y);
        v[6] = (short)f2bf(f1.z); v[7] = (short)f2bf(f1.w);
        *(bf16x8*)(xbf + (size_t)c * 8) = v;
    }
    // weight transposes
    for (int j = gtid; j < F_IN * HF; j += gsz) {
        int nn = j >> 9, k = j & (F_IN - 1);
        W1t[j] = f2bf(W1[(size_t)k * HF + nn]);
    }
    for (int j = gtid; j < HF * HF; j += gsz) {
        int nn = j >> 8, k = j & (HF - 1);
        W2t[j] = f2bf(W2[(size_t)k * HF + nn]);
    }
    // pad rows
    for (int j = gtid; j < padx; j += gsz) xbf[(size_t)n * F_IN + j] = 0;
    for (int j = gtid; j < pada; j += gsz) bufa_pad[j] = 0;
    // degree count last (packed 64-bit atomics; fire-and-forget, overlaps tail)
    for (int i = gtid; i < e; i += gsz) {
        unsigned long long add = (1ULL << 40)
            | (unsigned long long)__float2uint_rn(ew[i] * 1048576.0f);
        atomicAdd(&packed[col[i]], add);
    }
}

// ---------- scan1: block-local exclusive scan of counts ----------
__global__ void scan1_kernel(const unsigned long long* __restrict__ packed,
                             int* __restrict__ local, int* __restrict__ blocksum, int n) {
    __shared__ int tmp[SCAN_B];
    int i = blockIdx.x * SCAN_B + threadIdx.x;
    int v = (i < n) ? (int)(packed[i] >> 40) : 0;
    tmp[threadIdx.x] = v;
    __syncthreads();
    for (int off = 1; off < SCAN_B; off <<= 1) {
        int t = 0;
        if ((int)threadIdx.x >= off) t = tmp[threadIdx.x - off];
        __syncthreads();
        if ((int)threadIdx.x >= off) tmp[threadIdx.x] += t;
        __syncthreads();
    }
    if (i < n) local[i] = tmp[threadIdx.x] - v;       // exclusive
    if (threadIdx.x == SCAN_B - 1) blocksum[blockIdx.x] = tmp[SCAN_B - 1];
}

// ---------- scan3: add block prefix + dinv (self-loop added in INTEGER domain) ----------
__global__ void scan3_dinv_kernel(int* __restrict__ csr_ptr, int* __restrict__ cursor,
                                  const int* __restrict__ blocksum,
                                  const unsigned long long* __restrict__ packed,
                                  float* __restrict__ dinv, int n, int e, int nb) {
    __shared__ int red[SCAN_B];
    int t = threadIdx.x;
    red[t] = (t < nb && t < (int)blockIdx.x) ? blocksum[t] : 0;
    __syncthreads();
    for (int off = SCAN_B / 2; off > 0; off >>= 1) {
        if (t < off) red[t] += red[t + off];
        __syncthreads();
    }
    int prefix = red[0];
    int i = blockIdx.x * SCAN_B + t;
    if (i < n) {
        int val = csr_ptr[i] + prefix;
        csr_ptr[i] = val;
        cursor[i] = val;
        // + (1<<20) = self-loop weight 1.0 in 24.20 fixpoint (bit-identical to seeded init)
        float deg = (float)((packed[i] & 0xFFFFFFFFFFULL) + (1ULL << 20)) * (1.0f / 1048576.0f);
        dinv[i] = rsqrtf(deg);
    }
    if (i == 0) csr_ptr[n] = e;
}

// ---------- CSR fill: bucket edges by col, fold norm, 8B paired store ----------
__global__ void fill_kernel(const int* __restrict__ row, const int* __restrict__ col,
                            const float* __restrict__ w, const float* __restrict__ dinv,
                            int* __restrict__ cursor, int2* __restrict__ csr_edge, int e) {
    int i = blockIdx.x * blockDim.x + threadIdx.x;
    if (i < e) {
        int r = row[i], c = col[i];
        int pos = atomicAdd(&cursor[c], 1);
        float nrm = dinv[r] * w[i] * dinv[c];
        csr_edge[pos] = make_int2(r, __float_as_int(nrm));
    }
}

// ---------- m204 bijective XCD swizzle (round-robin blk->XCD assumption) ----------
__device__ inline int xcd_swizzle(int orig, int ngemm) {
    int xcd = orig & 7, j = orig >> 3;
    int q = ngemm >> 3, r8 = ngemm & 7;
    return (xcd < r8 ? xcd * (q + 1) : r8 * (q + 1) + (xcd - r8) * q) + j;
}

// ---------- pipelined bf16 GEMM: C[MP,256] = A[MP,K] @ Bt[256,K]^T ----------
// TAG distinguishes mangled names (layer 1 vs 2) for per-dispatch profiling.
template<int TAG>
__global__ __launch_bounds__(256)
void gemm_kernel(const unsigned short* __restrict__ A,
                 const unsigned short* __restrict__ Bt,
                 unsigned short* __restrict__ C, int K, int ngemm) {
    __shared__ unsigned short As[2][128 * LDSTR];
    __shared__ unsigned short Bs[2][128 * LDSTR];
    const int logical = xcd_swizzle(blockIdx.x, ngemm);
    const int m0 = (logical >> 1) * 128;
    const int n0 = (logical & 1) * 128;

    const int tid  = threadIdx.x;
    const int lane = tid & 63;
    const int wv   = tid >> 6;
    const int wrow = wv >> 1, wcol = wv & 1;

    const int sr = tid >> 2;          // staging row 0..63
    const int sc = (tid & 3) * 8;     // staging k-offset 0,8,16,24

    const unsigned short* pa0 = A + (size_t)(m0 + sr) * K + sc;
    const unsigned short* pa1 = A + (size_t)(m0 + sr + 64) * K + sc;
    const unsigned short* pb0 = Bt + (size_t)(n0 + sr) * K + sc;
    const unsigned short* pb1 = Bt + (size_t)(n0 + sr + 64) * K + sc;

    f32x4 zero4 = {0.0f, 0.0f, 0.0f, 0.0f};
    f32x4 acc[4][4];
    #pragma unroll
    for (int i = 0; i < 4; ++i)
        #pragma unroll
        for (int j = 0; j < 4; ++j) acc[i][j] = zero4;

    const int q8 = (lane >> 4) * 8;
    const int ml = lane & 15;

    bf16x8 va0 = *(const bf16x8*)pa0;
    bf16x8 va1 = *(const bf16x8*)pa1;
    bf16x8 vb0 = *(const bf16x8*)pb0;
    bf16x8 vb1 = *(const bf16x8*)pb1;

    const int nsteps = K >> 5;
    for (int s = 0; s < nsteps; ++s) {
        const int buf = s & 1;
        *(bf16x8*)&As[buf][sr * LDSTR + sc]        = va0;
        *(bf16x8*)&As[buf][(sr + 64) * LDSTR + sc] = va1;
        *(bf16x8*)&Bs[buf][sr * LDSTR + sc]        = vb0;
        *(bf16x8*)&Bs[buf][(sr + 64) * LDSTR + sc] = vb1;
        __syncthreads();
        if (s + 1 < nsteps) {             // prefetch next tile
            int off = (s + 1) * 32;
            va0 = *(const bf16x8*)(pa0 + off);
            va1 = *(const bf16x8*)(pa1 + off);
            vb0 = *(const bf16x8*)(pb0 + off);
            vb1 = *(const bf16x8*)(pb1 + off);
        }
        bf16x8 af[4], bfr[4];
        #pragma unroll
        for (int i = 0; i < 4; ++i)
            af[i] = *(const bf16x8*)&As[buf][(wrow * 64 + i * 16 + ml) * LDSTR + q8];
        #pragma unroll
        for (int j = 0; j < 4; ++j)
            bfr[j] = *(const bf16x8*)&Bs[buf][(wcol * 64 + j * 16 + ml) * LDSTR + q8];
        #pragma unroll
        for (int i = 0; i < 4; ++i)
            #pragma unroll
            for (int j = 0; j < 4; ++j)
                acc[i][j] = __builtin_amdgcn_mfma_f32_16x16x32_bf16(af[i], bfr[j], acc[i][j], 0, 0, 0);
    }

    // C store (bf16): col=lane&15, row=(lane>>4)*4+reg
    const int q4 = (lane >> 4) * 4;
    #pragma unroll
    for (int i = 0; i < 4; ++i) {
        #pragma unroll
        for (int j = 0; j < 4; ++j) {
            #pragma unroll
            for (int rg = 0; rg < 4; ++rg) {
                int r = m0 + wrow * 64 + i * 16 + q4 + rg;
                int c = n0 + wcol * 64 + j * 16 + ml;
                C[(size_t)r * HF + c] = f2bf(acc[i][j][rg]);
            }
        }
    }
}

// ---------- fused CSR gather + self-loop + bias + BN + ReLU (R2 body) ----------
// one wave per node; 2 edges per gather instruction (lane halves), 8 feats/lane.
#define AGBL 8   // loads per main batch; each load covers 2 edges
template<int FINAL>
__global__ void agg_kernel(const unsigned short* __restrict__ h,
                           const int* __restrict__ ptr,
                           const int2* __restrict__ edge,
                           const float* __restrict__ dinv,
                           const float* __restrict__ b, const float* __restrict__ g,
                           const float* __restrict__ be, const float* __restrict__ m,
                           const float* __restrict__ v,
                           unsigned short* __restrict__ out,
                           const float* __restrict__ W3, float* __restrict__ h3, int n) {
    int wid  = (blockIdx.x * blockDim.x + threadIdx.x) >> 6;
    int lane = threadIdx.x & 63;
    if (wid >= n) return;
    const int hi = lane >> 5;          // which edge of the pair this half handles
    const int l  = lane & 31;
    const int fo = l * 8;              // 8 features per lane (16B)

    int p0 = ptr[wid], p1 = ptr[wid + 1];
    int deg = p1 - p0;

    float a0 = 0.f, a1 = 0.f, a2 = 0.f, a3 = 0.f;
    float a4 = 0.f, a5 = 0.f, a6 = 0.f, a7 = 0.f;

    // ---- main: batches of 16 edges (8 paired loads) ----
    const int nb = deg & ~15;
    for (int t = 0; t < nb; t += 16) {
        int2 ed[AGBL];
        #pragma unroll
        for (int k = 0; k < AGBL; ++k) ed[k] = edge[p0 + t + 2 * k + hi];
        u16x8 hv[AGBL];
        #pragma unroll
        for (int k = 0; k < AGBL; ++k)
            hv[k] = *(const u16x8*)(h + (size_t)(unsigned)ed[k].x * HF + fo);
        #pragma unroll
        for (int k = 0; k < AGBL; ++k) {
            float nw = __int_as_float(ed[k].y);
            a0 += nw * bf2f(hv[k][0]);
            a1 += nw * bf2f(hv[k][1]);
            a2 += nw * bf2f(hv[k][2]);
            a3 += nw * bf2f(hv[k][3]);
            a4 += nw * bf2f(hv[k][4]);
            a5 += nw * bf2f(hv[k][5]);
            a6 += nw * bf2f(hv[k][6]);
            a7 += nw * bf2f(hv[k][7]);
        }
    }
    // ---- tail: 4-edge clamped steps (2 paired loads) ----
    for (int t = nb; t < deg; t += 4) {
        int2 ed[2];
        float wv2[2];
        #pragma unroll
        for (int j = 0; j < 2; ++j) {
            int idx = t + 2 * j + hi;
            int cl = idx < deg ? idx : 0;     // deg >= 1 here, edge[p0] valid
            ed[j] = edge[p0 + cl];
            wv2[j] = (idx < deg) ? __int_as_float(ed[j].y) : 0.0f;
        }
        u16x8 hv[2];
        #pragma unroll
        for (int j = 0; j < 2; ++j)
            hv[j] = *(const u16x8*)(h + (size_t)(unsigned)ed[j].x * HF + fo);
        #pragma unroll
        for (int j = 0; j < 2; ++j) {
            float nw = wv2[j];
            a0 += nw * bf2f(hv[j][0]);
            a1 += nw * bf2f(hv[j][1]);
            a2 += nw * bf2f(hv[j][2]);
            a3 += nw * bf2f(hv[j][3]);
            a4 += nw * bf2f(hv[j][4]);
            a5 += nw * bf2f(hv[j][5]);
            a6 += nw * bf2f(hv[j][6]);
            a7 += nw * bf2f(hv[j][7]);
        }
    }

    // combine the two halves (lanes l and l+32 hold same features, different edges)
    a0 += __shfl_xor(a0, 32, 64);
    a1 += __shfl_xor(a1, 32, 64);
    a2 += __shfl_xor(a2, 32, 64);
    a3 += __shfl_xor(a3, 32, 64);
    a4 += __shfl_xor(a4, 32, 64);
    a5 += __shfl_xor(a5, 32, 64);
    a6 += __shfl_xor(a6, 32, 64);
    a7 += __shfl_xor(a7, 32, 64);

    // self loop: weight 1, norm = dinv^2 (all lanes hold identical totals now)
    float s = dinv[wid];
    float sl = s * s;
    u16x8 hs = *(const u16x8*)(h + (size_t)wid * HF + fo);
    a0 += sl * bf2f(hs[0]);
    a1 += sl * bf2f(hs[1]);
    a2 += sl * bf2f(hs[2]);
    a3 += sl * bf2f(hs[3]);
    a4 += sl * bf2f(hs[4]);
    a5 += sl * bf2f(hs[5]);
    a6 += sl * bf2f(hs[6]);
    a7 += sl * bf2f(hs[7]);

    float4 bb0  = *(const float4*)(b + fo),      bb1  = *(const float4*)(b + fo + 4);
    float4 gg0  = *(const float4*)(g + fo),      gg1  = *(const float4*)(g + fo + 4);
    float4 bee0 = *(const float4*)(be + fo),     bee1 = *(const float4*)(be + fo + 4);
    float4 mm0  = *(const float4*)(m + fo),      mm1  = *(const float4*)(m + fo + 4);
    float4 vv0  = *(const float4*)(v + fo),      vv1  = *(const float4*)(v + fo + 4);
    float f0 = fmaxf((a0 + bb0.x - mm0.x) * rsqrtf(vv0.x + BN_EPS) * gg0.x + bee0.x, 0.f);
    float f1 = fmaxf((a1 + bb0.y - mm0.y) * rsqrtf(vv0.y + BN_EPS) * gg0.y + bee0.y, 0.f);
    float f2 = fmaxf((a2 + bb0.z - mm0.z) * rsqrtf(vv0.z + BN_EPS) * gg0.z + bee0.z, 0.f);
    float f3 = fmaxf((a3 + bb0.w - mm0.w) * rsqrtf(vv0.w + BN_EPS) * gg0.w + bee0.w, 0.f);
    float f4 = fmaxf((a4 + bb1.x - mm1.x) * rsqrtf(vv1.x + BN_EPS) * gg1.x + bee1.x, 0.f);
    float f5 = fmaxf((a5 + bb1.y - mm1.y) * rsqrtf(vv1.y + BN_EPS) * gg1.y + bee1.y, 0.f);
    float f6 = fmaxf((a6 + bb1.z - mm1.z) * rsqrtf(vv1.z + BN_EPS) * gg1.z + bee1.z, 0.f);
    float f7 = fmaxf((a7 + bb1.w - mm1.w) * rsqrtf(vv1.w + BN_EPS) * gg1.w + bee1.w, 0.f);

    if (!FINAL) {
        if (hi == 0) {                     // lanes 0..31 cover all 256 feats
            u16x8 o;
            o[0] = f2bf(f0); o[1] = f2bf(f1); o[2] = f2bf(f2); o[3] = f2bf(f3);
            o[4] = f2bf(f4); o[5] = f2bf(f5); o[6] = f2bf(f6); o[7] = f2bf(f7);
            *(u16x8*)(out + (size_t)wid * HF + fo) = o;
        }
    } else {
        // fused layer-3 GEMV: h3[wid, o] = sum_f act[f] * W3[f][o]
        float4 w0 = *(const float4*)(W3 + fo * 2);
        float4 w1 = *(const float4*)(W3 + fo * 2 + 4);
        float4 w2 = *(const float4*)(W3 + fo * 2 + 8);
        float4 w3 = *(const float4*)(W3 + fo * 2 + 12);
        float s0 = f0 * w0.x + f1 * w0.z + f2 * w1.x + f3 * w1.z
                 + f4 * w2.x + f5 * w2.z + f6 * w3.x + f7 * w3.z;
        float s1 = f0 * w0.y + f1 * w0.w + f2 * w1.y + f3 * w1.w
                 + f4 * w2.y + f5 * w2.w + f6 * w3.y + f7 * w3.w;
        // halves hold identical values; reduce within the 32-lane half
        #pragma unroll
        for (int o = 16; o > 0; o >>= 1) {
            s0 += __shfl_xor(s0, o, 64);
            s1 += __shfl_xor(s1, o, 64);
        }
        if (lane == 0) {
            h3[wid * 2 + 0] = s0;
            h3[wid * 2 + 1] = s1;
        }
    }
}

// ---------- final: CSR gather (2 features) + self-loop + bias ----------
__global__ void out_kernel(const float* __restrict__ h3,
                           const int* __restrict__ ptr, const int2* __restrict__ edge,
                           const float* __restrict__ dinv,
                           const float* __restrict__ b3, float* __restrict__ out, int n) {
    int i = blockIdx.x * blockDim.x + threadIdx.x;
    if (i >= n) return;
    int p0 = ptr[i], p1 = ptr[i + 1];
    float a0 = 0.f, a1 = 0.f;
    for (int p = p0; p < p1; p += 4) {
        #pragma unroll
        for (int k = 0; k < 4; ++k) {
            int idx = p + k < p1 ? p + k : p1 - 1;
            int2 e = edge[idx];
            float nw = (p + k < p1) ? __int_as_float(e.y) : 0.0f;
            float2 u = *(const float2*)(h3 + 2 * e.x);
            a0 += nw * u.x;
            a1 += nw * u.y;
        }
    }
    float s = dinv[i];
    float sl = s * s;
    out[2 * i + 0] = a0 + sl * h3[2 * i + 0] + b3[0];
    out[2 * i + 1] = a1 + sl * h3[2 * i + 1] + b3[1];
}

static inline char* align16(char* p) {
    return (char*)(((uintptr_t)p + 15) & ~(uintptr_t)15);
}

extern "C" void kernel_launch(void* const* d_in, const int* in_sizes, int n_in,
                              void* d_out, int out_size, void* d_ws, size_t ws_size,
                              hipStream_t stream) {
    const float* x   = (const float*)d_in[0];
    const int*   ei  = (const int*)d_in[1];    // int64 in reference -> int32 in harness
    const float* ew  = (const float*)d_in[2];
    const float* W1  = (const float*)d_in[3];
    const float* b1  = (const float*)d_in[4];
    const float* g1  = (const float*)d_in[5];
    const float* be1 = (const float*)d_in[6];
    const float* m1  = (const float*)d_in[7];
    const float* v1  = (const float*)d_in[8];
    const float* W2  = (const float*)d_in[9];
    const float* b2  = (const float*)d_in[10];
    const float* g2  = (const float*)d_in[11];
    const float* be2 = (const float*)d_in[12];
    const float* m2  = (const float*)d_in[13];
    const float* v2  = (const float*)d_in[14];
    const float* W3  = (const float*)d_in[15];
    const float* b3  = (const float*)d_in[16];

    const int N  = in_sizes[0] / F_IN;         // 50000
    const int E  = in_sizes[2];                // 800000
    const int MP = (N + 127) & ~127;           // 50048
    const int* row = ei;
    const int* col = ei + E;

    char* wsb = (char*)d_ws;
    unsigned long long* packed = (unsigned long long*)wsb; wsb = align16(wsb + (size_t)N * 8);
    float* dinv     = (float*)wsb;          wsb = align16(wsb + (size_t)N * 4);
    int*   csr_ptr  = (int*)wsb;            wsb = align16(wsb + (size_t)(N + 1) * 4);
    int*   cursor   = (int*)wsb;            wsb = align16(wsb + (size_t)N * 4);
    int*   blocksum = (int*)wsb;            wsb = align16(wsb + (size_t)SCAN_B * 4);
    int2*  csr_edge = (int2*)wsb;           wsb = align16(wsb + (size_t)E * 8);
    unsigned short* W1t = (unsigned short*)wsb;  wsb = align16(wsb + (size_t)F_IN * HF * 2);
    unsigned short* W2t = (unsigned short*)wsb;  wsb = align16(wsb + (size_t)HF * HF * 2);
    unsigned short* xbf  = (unsigned short*)wsb; wsb = align16(wsb + (size_t)MP * F_IN * 2);
    unsigned short* bufh = (unsigned short*)wsb; wsb = align16(wsb + (size_t)MP * HF * 2);
    unsigned short* bufa = (unsigned short*)wsb; wsb = align16(wsb + (size_t)MP * HF * 2);
    float* h3 = (float*)wsb;                wsb = align16(wsb + (size_t)N * OUT_F * 4);
    float* outf = (float*)d_out;

    const int TB = 256;
    const int nscan = (N + SCAN_B - 1) / SCAN_B;        // 196
    const int padx = (MP - N) * F_IN;
    const int pada = (MP - N) * HF;
    const int nchunk = (N * F_IN) / 8;                  // 3.2M bf16x8 chunks
    const int ngemm = (MP / 128) * 2;                   // 782

    // --- packed counts start at zero (self-loop folded into scan3) ---
    (void)hipMemsetAsync(packed, 0, (size_t)N * 8, stream);

    // --- front: x->bf16 (MLP-4) + W transposes + pads + degree count ---
    front_kernel<<<2048, TB, 0, stream>>>(
        packed, W1, W1t, W2, W2t, x, xbf, bufa + (size_t)N * HF,
        col, ew, N, E, padx, pada, nchunk);

    // --- CSR build ---
    scan1_kernel<<<nscan, SCAN_B, 0, stream>>>(packed, csr_ptr, blocksum, N);
    scan3_dinv_kernel<<<nscan, SCAN_B, 0, stream>>>(csr_ptr, cursor, blocksum, packed, dinv, N, E, nscan);
    fill_kernel<<<(E + TB - 1) / TB, TB, 0, stream>>>(row, col, ew, dinv, cursor, csr_edge, E);

    // --- layer 1 ---
    gemm_kernel<1><<<ngemm, TB, 0, stream>>>(xbf, W1t, bufh, F_IN, ngemm);
    agg_kernel<0><<<((size_t)N * 64 + TB - 1) / TB, TB, 0, stream>>>(
        bufh, csr_ptr, csr_edge, dinv, b1, g1, be1, m1, v1, bufa, nullptr, nullptr, N);

    // --- layer 2 ---
    gemm_kernel<2><<<ngemm, TB, 0, stream>>>(bufa, W2t, bufh, HF, ngemm);
    agg_kernel<1><<<((size_t)N * 64 + TB - 1) / TB, TB, 0, stream>>>(
        bufh, csr_ptr, csr_edge, dinv, b2, g2, be2, m2, v2, nullptr, W3, h3, N);

    // --- final 2-feature aggregation ---
    out_kernel<<<(N + TB - 1) / TB, TB, 0, stream>>>(h3, csr_ptr, csr_edge, dinv, b3, outf, N);
}